// Round 1
// baseline (891.749 us; speedup 1.0000x reference)
//
#include <hip/hip_runtime.h>
#include <hip/hip_bf16.h>

#define NB 16
#define NP 1024
#define CF 768
#define CC 512
#define HH 28
#define WW 28
#define HW 784
#define NTOT 16777216.0f  // 16*1024*1024

typedef short bf16x8 __attribute__((ext_vector_type(8)));
typedef float f32x4 __attribute__((ext_vector_type(4)));

// ---------------------------------------------------------------- transpose
// (B, C, HW) f32 -> (B, HW, C) f32, LDS-tiled, coalesced both sides.
__global__ void transpose_kernel(const float* __restrict__ in,
                                 float* __restrict__ out, int C) {
  __shared__ float tile[32][33];
  int p0 = blockIdx.x * 32, c0 = blockIdx.y * 32, b = blockIdx.z;
  int tx = threadIdx.x, ty = threadIdx.y;
  const float* ib = in + (size_t)b * C * HW;
  float* ob = out + (size_t)b * HW * C;
#pragma unroll
  for (int i = 0; i < 32; i += 8) {
    int c = c0 + ty + i, p = p0 + tx;
    if (p < HW) tile[ty + i][tx] = ib[(size_t)c * HW + p];
  }
  __syncthreads();
#pragma unroll
  for (int i = 0; i < 32; i += 8) {
    int p = p0 + ty + i, c = c0 + tx;
    if (p < HW) ob[(size_t)p * C + c] = tile[tx][ty + i];
  }
}

// ---------------------------------------------------------------- sampling
// One block per (position p, batch b): bilinear sample 768 feat + 512 code
// channels from channel-last tensors, L2-normalize over channels, store bf16.
// perm==nullptr -> source batch = b, else source batch = perm[b].
__global__ void sample_norm_kernel(const float* __restrict__ fT,
                                   const float* __restrict__ cT,
                                   const float* __restrict__ coords,
                                   const int* __restrict__ perm,
                                   __hip_bfloat16* __restrict__ outF,
                                   __hip_bfloat16* __restrict__ outC) {
  __shared__ float red[4];
  int p = blockIdx.x;
  int b = blockIdx.y;
  int tid = threadIdx.x;
  int w = tid >> 6, ln = tid & 63;
  int srcb = perm ? perm[b] : b;

  float cx = coords[((size_t)b * NP + p) * 2 + 0];
  float cy = coords[((size_t)b * NP + p) * 2 + 1];
  // reference: grid=(c*2-1); x=(g+1)*0.5*(W-1) == c*(W-1)
  float x = cx * (WW - 1), y = cy * (HH - 1);
  float x0f = floorf(x), y0f = floorf(y);
  float wx = x - x0f, wy = y - y0f;
  int x0 = min(max((int)x0f, 0), WW - 1);
  int x1 = min(max((int)x0f + 1, 0), WW - 1);
  int y0 = min(max((int)y0f, 0), HH - 1);
  int y1 = min(max((int)y0f + 1, 0), HH - 1);
  float wa = (1.f - wx) * (1.f - wy);
  float wb = (1.f - wx) * wy;
  float wc = wx * (1.f - wy);
  float wd = wx * wy;

  // -------- feats (768 = 3 per thread)
  const float* fb = fT + (size_t)srcb * HW * CF;
  const float* ra = fb + (size_t)(y0 * WW + x0) * CF;
  const float* rb = fb + (size_t)(y1 * WW + x0) * CF;
  const float* rc = fb + (size_t)(y0 * WW + x1) * CF;
  const float* rd = fb + (size_t)(y1 * WW + x1) * CF;
  float v[3];
  float ss = 0.f;
#pragma unroll
  for (int j = 0; j < 3; ++j) {
    int c = tid + j * 256;
    float t = wa * ra[c] + wb * rb[c] + wc * rc[c] + wd * rd[c];
    v[j] = t;
    ss += t * t;
  }
#pragma unroll
  for (int m = 1; m < 64; m <<= 1) ss += __shfl_xor(ss, m);
  if (ln == 0) red[w] = ss;
  __syncthreads();
  ss = red[0] + red[1] + red[2] + red[3];
  float sc = 1.f / fmaxf(sqrtf(ss), 1e-10f);
  __hip_bfloat16* of = outF + ((size_t)b * NP + p) * CF;
#pragma unroll
  for (int j = 0; j < 3; ++j) of[tid + j * 256] = __float2bfloat16(v[j] * sc);
  __syncthreads();  // red[] reuse barrier

  // -------- code (512 = 2 per thread)
  const float* cb = cT + (size_t)srcb * HW * CC;
  const float* ca = cb + (size_t)(y0 * WW + x0) * CC;
  const float* cbb = cb + (size_t)(y1 * WW + x0) * CC;
  const float* cc = cb + (size_t)(y0 * WW + x1) * CC;
  const float* cd = cb + (size_t)(y1 * WW + x1) * CC;
  float u[2];
  float ss2 = 0.f;
#pragma unroll
  for (int j = 0; j < 2; ++j) {
    int c = tid + j * 256;
    float t = wa * ca[c] + wb * cbb[c] + wc * cc[c] + wd * cd[c];
    u[j] = t;
    ss2 += t * t;
  }
#pragma unroll
  for (int m = 1; m < 64; m <<= 1) ss2 += __shfl_xor(ss2, m);
  if (ln == 0) red[w] = ss2;
  __syncthreads();
  ss2 = red[0] + red[1] + red[2] + red[3];
  float sc2 = 1.f / fmaxf(sqrtf(ss2), 1e-10f);
  __hip_bfloat16* oc = outC + ((size_t)b * NP + p) * CC;
#pragma unroll
  for (int j = 0; j < 2; ++j) oc[tid + j * 256] = __float2bfloat16(u[j] * sc2);
}

// ---------------------------------------------------------------- fused corr
// Stage a 128x32 bf16 tile into LDS in MFMA-chunk order [kq][row][8elem]
// via global_load_lds width=16 (LDS dest = wave-uniform base + lane*16).
__device__ __forceinline__ void stage_tile(const __hip_bfloat16* __restrict__ src,
                                           int row0, int k0, int ld,
                                           bf16x8* buf, int tid) {
#pragma unroll
  for (int i = 0; i < 2; ++i) {
    int c = i * 256 + tid;        // chunk index = kq*128 + m
    int kq = c >> 7, m = c & 127;
    const __hip_bfloat16* g = src + (size_t)(row0 + m) * ld + (k0 + kq * 8);
    __builtin_amdgcn_global_load_lds(
        (const __attribute__((address_space(1))) void*)g,
        (__attribute__((address_space(3))) void*)&buf[i * 256 + (tid & 192)],
        16, 0, 0);
  }
}

// grid (8,8,64): z = h*16 + b. Block 256 = 4 waves, each wave 64x64 (4x4 MFMA).
// Computes fd tile (K=768) and cd tile (K=512), then reduces:
//   rowfd[h,b,p]  += sum_q fd        rowrcd[h,b,p] += sum_q relu(cd)
//   cross[h]      += sum relu(cd)*fd
__global__ __launch_bounds__(256, 2) void corr_kernel(
    const __hip_bfloat16* __restrict__ Fb, const __hip_bfloat16* __restrict__ Cb,
    float* __restrict__ rowfd, float* __restrict__ rowrcd,
    float* __restrict__ cross) {
  __shared__ bf16x8 As[512];  // 8 KB
  __shared__ bf16x8 Bs[512];  // 8 KB

  int z = blockIdx.z;
  int h = z >> 4, bb = z & 15;
  int p0 = blockIdx.x * 128, q0 = blockIdx.y * 128;
  int tid = threadIdx.x, ln = tid & 63, w = tid >> 6;
  int wm = w >> 1, wn = w & 1, quad = ln >> 4, t16 = ln & 15;

  const __hip_bfloat16* Af = Fb + (size_t)bb * (NP * CF);                 // f1 = feats
  const __hip_bfloat16* Bf = Fb + ((size_t)h * NB + bb) * (NP * CF);     // f2 per helper
  const __hip_bfloat16* Ac = Cb + (size_t)bb * (NP * CC);                 // c1 = code
  const __hip_bfloat16* Bc = Cb + ((size_t)h * NB + bb) * (NP * CC);     // c2 per helper

  f32x4 accf[4][4], accc[4][4];
#pragma unroll
  for (int i = 0; i < 4; ++i)
#pragma unroll
    for (int j = 0; j < 4; ++j) {
      accf[i][j] = (f32x4){0.f, 0.f, 0.f, 0.f};
      accc[i][j] = (f32x4){0.f, 0.f, 0.f, 0.f};
    }

  // ---- fd GEMM: K = 768
  for (int kt = 0; kt < CF / 32; ++kt) {
    stage_tile(Af, p0, kt * 32, CF, As, tid);
    stage_tile(Bf, q0, kt * 32, CF, Bs, tid);
    __syncthreads();
    bf16x8 a[4], b[4];
#pragma unroll
    for (int mi = 0; mi < 4; ++mi) a[mi] = As[quad * 128 + wm * 64 + mi * 16 + t16];
#pragma unroll
    for (int ni = 0; ni < 4; ++ni) b[ni] = Bs[quad * 128 + wn * 64 + ni * 16 + t16];
#pragma unroll
    for (int mi = 0; mi < 4; ++mi)
#pragma unroll
      for (int ni = 0; ni < 4; ++ni)
        accf[mi][ni] = __builtin_amdgcn_mfma_f32_16x16x32_bf16(a[mi], b[ni],
                                                               accf[mi][ni], 0, 0, 0);
    __syncthreads();
  }
  // ---- cd GEMM: K = 512
  for (int kt = 0; kt < CC / 32; ++kt) {
    stage_tile(Ac, p0, kt * 32, CC, As, tid);
    stage_tile(Bc, q0, kt * 32, CC, Bs, tid);
    __syncthreads();
    bf16x8 a[4], b[4];
#pragma unroll
    for (int mi = 0; mi < 4; ++mi) a[mi] = As[quad * 128 + wm * 64 + mi * 16 + t16];
#pragma unroll
    for (int ni = 0; ni < 4; ++ni) b[ni] = Bs[quad * 128 + wn * 64 + ni * 16 + t16];
#pragma unroll
    for (int mi = 0; mi < 4; ++mi)
#pragma unroll
      for (int ni = 0; ni < 4; ++ni)
        accc[mi][ni] = __builtin_amdgcn_mfma_f32_16x16x32_bf16(a[mi], b[ni],
                                                               accc[mi][ni], 0, 0, 0);
    __syncthreads();
  }

  // ---- epilogue: C/D layout row = quad*4 + reg, col = t16
  float cross_l = 0.f;
#pragma unroll
  for (int mi = 0; mi < 4; ++mi) {
#pragma unroll
    for (int r = 0; r < 4; ++r) {
      float sfd = 0.f, srw = 0.f;
#pragma unroll
      for (int ni = 0; ni < 4; ++ni) {
        float fd = accf[mi][ni][r];
        float cd = accc[mi][ni][r];
        float rc = fmaxf(cd, 0.f);
        sfd += fd;
        srw += rc;
        cross_l += rc * fd;
      }
#pragma unroll
      for (int m = 1; m < 16; m <<= 1) {
        sfd += __shfl_xor(sfd, m);
        srw += __shfl_xor(srw, m);
      }
      if (t16 == 0) {
        int p = p0 + wm * 64 + mi * 16 + quad * 4 + r;
        size_t idx = ((size_t)h * NB + bb) * NP + p;
        atomicAdd(&rowfd[idx], sfd);
        atomicAdd(&rowrcd[idx], srw);
      }
    }
  }
#pragma unroll
  for (int m = 1; m < 64; m <<= 1) cross_l += __shfl_xor(cross_l, m);
  if (ln == 0) atomicAdd(&cross[h], cross_l);
}

// ---------------------------------------------------------------- finalize
__global__ void finalize_kernel(const float* __restrict__ rowfd,
                                const float* __restrict__ rowrcd,
                                const float* __restrict__ cross,
                                float* __restrict__ out) {
  __shared__ float r1[4], r2[4], r3[4];
  __shared__ float losses[4];
  const float shifts[4] = {0.18f, 0.12f, 0.46f, 0.46f};
  int tid = threadIdx.x, w = tid >> 6, ln = tid & 63;
  for (int h = 0; h < 4; ++h) {
    float s1 = 0.f, s2 = 0.f, s3 = 0.f;
    for (int i = tid; i < NB * NP; i += 256) {
      float a = rowfd[h * NB * NP + i];
      float c = rowrcd[h * NB * NP + i];
      s1 += a;
      s2 += c;
      s3 += a * c;
    }
#pragma unroll
    for (int m = 1; m < 64; m <<= 1) {
      s1 += __shfl_xor(s1, m);
      s2 += __shfl_xor(s2, m);
      s3 += __shfl_xor(s3, m);
    }
    if (ln == 0) { r1[w] = s1; r2[w] = s2; r3[w] = s3; }
    __syncthreads();
    if (tid == 0) {
      float Sfd = r1[0] + r1[1] + r1[2] + r1[3];
      float Srcd = r2[0] + r2[1] + r2[2] + r2[3];
      float Sdot = r3[0] + r3[1] + r3[2] + r3[3];
      float cr = cross[h];
      losses[h] = -(cr - Sdot * (1.0f / 1024.0f) + (Sfd / NTOT - shifts[h]) * Srcd) / NTOT;
    }
    __syncthreads();
  }
  if (tid == 0) {
    out[0] = losses[0];
    out[1] = losses[1];
    out[2] = 0.5f * (losses[2] + losses[3]);
  }
}

// ---------------------------------------------------------------- launch
extern "C" void kernel_launch(void* const* d_in, const int* in_sizes, int n_in,
                              void* d_out, int out_size, void* d_ws, size_t ws_size,
                              hipStream_t stream) {
  (void)in_sizes; (void)n_in; (void)out_size; (void)ws_size;
  const float* orig_feats = (const float*)d_in[0];
  const float* orig_feats_pos = (const float*)d_in[1];
  const float* orig_code = (const float*)d_in[4];
  const float* orig_code_pos = (const float*)d_in[5];
  const float* coords1 = (const float*)d_in[8];
  const float* coords2 = (const float*)d_in[9];
  const int* perms = (const int*)d_in[10];
  float* out = (float*)d_out;

  char* ws = (char*)d_ws;
  size_t off = 0;
  float* featsT = (float*)(ws + off); off += (size_t)NB * HW * CF * 4;      // 38.5 MB
  float* codeT  = (float*)(ws + off); off += (size_t)NB * HW * CC * 4;      // 25.7 MB
  __hip_bfloat16* Fb = (__hip_bfloat16*)(ws + off); off += (size_t)4 * NB * NP * CF * 2;  // 100.7 MB
  __hip_bfloat16* Cb = (__hip_bfloat16*)(ws + off); off += (size_t)4 * NB * NP * CC * 2;  // 67.1 MB
  float* rowfd  = (float*)(ws + off); off += (size_t)4 * NB * NP * 4;
  float* rowrcd = (float*)(ws + off); off += (size_t)4 * NB * NP * 4;
  float* cross  = (float*)(ws + off); off += 64;

  const size_t FSTR = (size_t)NB * NP * CF;  // per-helper feats stride (elems)
  const size_t CSTR = (size_t)NB * NP * CC;

  // zero the accumulation buffers (rowfd | rowrcd | cross contiguous)
  (void)hipMemsetAsync(rowfd, 0, (size_t)4 * NB * NP * 4 * 2 + 64, stream);

  dim3 tb(32, 8);
  // pass 1: self tensors -> sample h0 (self@c1), h2/h3 (neg@c2, permuted batch)
  transpose_kernel<<<dim3(25, 24, 16), tb, 0, stream>>>(orig_feats, featsT, CF);
  transpose_kernel<<<dim3(25, 16, 16), tb, 0, stream>>>(orig_code, codeT, CC);
  sample_norm_kernel<<<dim3(NP, NB), 256, 0, stream>>>(featsT, codeT, coords1, nullptr,
                                                       Fb + 0 * FSTR, Cb + 0 * CSTR);
  sample_norm_kernel<<<dim3(NP, NB), 256, 0, stream>>>(featsT, codeT, coords2, perms + 0,
                                                       Fb + 2 * FSTR, Cb + 2 * CSTR);
  sample_norm_kernel<<<dim3(NP, NB), 256, 0, stream>>>(featsT, codeT, coords2, perms + 16,
                                                       Fb + 3 * FSTR, Cb + 3 * CSTR);
  // pass 2: pos tensors reuse the transpose buffers -> sample h1 (pos@c2)
  transpose_kernel<<<dim3(25, 24, 16), tb, 0, stream>>>(orig_feats_pos, featsT, CF);
  transpose_kernel<<<dim3(25, 16, 16), tb, 0, stream>>>(orig_code_pos, codeT, CC);
  sample_norm_kernel<<<dim3(NP, NB), 256, 0, stream>>>(featsT, codeT, coords2, nullptr,
                                                       Fb + 1 * FSTR, Cb + 1 * CSTR);

  corr_kernel<<<dim3(8, 8, 64), 256, 0, stream>>>(Fb, Cb, rowfd, rowrcd, cross);
  finalize_kernel<<<1, 256, 0, stream>>>(rowfd, rowrcd, cross, out);
}

// Round 2
// 750.552 us; speedup vs baseline: 1.1881x; 1.1881x over previous
//
#include <hip/hip_runtime.h>
#include <hip/hip_bf16.h>

#define NB 16
#define NP 1024
#define CF 768
#define CC 512
#define HH 28
#define WW 28
#define HW 784
#define NTOT 16777216.0f  // 16*1024*1024

typedef short bf16x8 __attribute__((ext_vector_type(8)));
typedef float f32x4 __attribute__((ext_vector_type(4)));

// ---------------------------------------------------------------- transpose
// (B, C, HW) f32 -> (B, HW, C) f32, LDS-tiled, coalesced both sides.
__global__ void transpose_kernel(const float* __restrict__ in,
                                 float* __restrict__ out, int C) {
  __shared__ float tile[32][33];
  int p0 = blockIdx.x * 32, c0 = blockIdx.y * 32, b = blockIdx.z;
  int tx = threadIdx.x, ty = threadIdx.y;
  const float* ib = in + (size_t)b * C * HW;
  float* ob = out + (size_t)b * HW * C;
#pragma unroll
  for (int i = 0; i < 32; i += 8) {
    int c = c0 + ty + i, p = p0 + tx;
    if (p < HW) tile[ty + i][tx] = ib[(size_t)c * HW + p];
  }
  __syncthreads();
#pragma unroll
  for (int i = 0; i < 32; i += 8) {
    int p = p0 + ty + i, c = c0 + tx;
    if (p < HW) ob[(size_t)p * C + c] = tile[tx][ty + i];
  }
}

// ---------------------------------------------------------------- sampling
// Block = 192 threads (3 waves), one block per (position, batch, variant).
// float4 gathers from channel-last tensors; L2-normalize; store bf16 (8B).
// pass 0: z=0 -> coords1/self/slot0, z=1 -> coords2/perm0/slot2,
//         z=2 -> coords2/perm1/slot3.   pass 1: coords2/self/slot1.
struct bf4 { __hip_bfloat16 a, b, c, d; };

__global__ void sample_norm_kernel(const float* __restrict__ fT,
                                   const float* __restrict__ cT,
                                   const float* __restrict__ coords1,
                                   const float* __restrict__ coords2,
                                   const int* __restrict__ perms, int pass,
                                   __hip_bfloat16* __restrict__ Fb,
                                   __hip_bfloat16* __restrict__ Cb) {
  __shared__ float red[4];
  int p = blockIdx.x, b = blockIdx.y, z = blockIdx.z;
  int tid = threadIdx.x, w = tid >> 6, ln = tid & 63;

  const float* coords;
  int srcb, slot;
  if (pass == 0) {
    if (z == 0)      { coords = coords1; srcb = b;            slot = 0; }
    else if (z == 1) { coords = coords2; srcb = perms[b];     slot = 2; }
    else             { coords = coords2; srcb = perms[16 + b]; slot = 3; }
  } else             { coords = coords2; srcb = b;            slot = 1; }

  float cx = coords[((size_t)b * NP + p) * 2 + 0];
  float cy = coords[((size_t)b * NP + p) * 2 + 1];
  float x = cx * (WW - 1), y = cy * (HH - 1);   // (c*2-1 +1)*0.5*(W-1)
  float x0f = floorf(x), y0f = floorf(y);
  float wx = x - x0f, wy = y - y0f;
  int x0 = min(max((int)x0f, 0), WW - 1);
  int x1 = min(max((int)x0f + 1, 0), WW - 1);
  int y0 = min(max((int)y0f, 0), HH - 1);
  int y1 = min(max((int)y0f + 1, 0), HH - 1);
  float wa = (1.f - wx) * (1.f - wy);
  float wb = (1.f - wx) * wy;
  float wc = wx * (1.f - wy);
  float wd = wx * wy;

  // -------- feats: 192 threads x float4 = 768 channels
  const float4* ra = (const float4*)(fT + ((size_t)srcb * HW + y0 * WW + x0) * CF);
  const float4* rb = (const float4*)(fT + ((size_t)srcb * HW + y1 * WW + x0) * CF);
  const float4* rc = (const float4*)(fT + ((size_t)srcb * HW + y0 * WW + x1) * CF);
  const float4* rd = (const float4*)(fT + ((size_t)srcb * HW + y1 * WW + x1) * CF);
  float4 A = ra[tid], Bv = rb[tid], Cv = rc[tid], D = rd[tid];
  float4 v;
  v.x = wa * A.x + wb * Bv.x + wc * Cv.x + wd * D.x;
  v.y = wa * A.y + wb * Bv.y + wc * Cv.y + wd * D.y;
  v.z = wa * A.z + wb * Bv.z + wc * Cv.z + wd * D.z;
  v.w = wa * A.w + wb * Bv.w + wc * Cv.w + wd * D.w;
  float ss = v.x * v.x + v.y * v.y + v.z * v.z + v.w * v.w;
#pragma unroll
  for (int m = 1; m < 64; m <<= 1) ss += __shfl_xor(ss, m);
  if (ln == 0) red[w] = ss;
  __syncthreads();
  ss = red[0] + red[1] + red[2];
  float sc = 1.f / fmaxf(sqrtf(ss), 1e-10f);
  bf4 of = {__float2bfloat16(v.x * sc), __float2bfloat16(v.y * sc),
            __float2bfloat16(v.z * sc), __float2bfloat16(v.w * sc)};
  ((bf4*)(Fb + ((size_t)slot * NB * NP + (size_t)b * NP + p) * CF))[tid] = of;
  __syncthreads();  // red[] reuse

  // -------- code: threads 0..127 x float4 = 512 channels
  float4 u = {0.f, 0.f, 0.f, 0.f};
  float ss2 = 0.f;
  if (tid < 128) {
    const float4* ca = (const float4*)(cT + ((size_t)srcb * HW + y0 * WW + x0) * CC);
    const float4* cb = (const float4*)(cT + ((size_t)srcb * HW + y1 * WW + x0) * CC);
    const float4* cc = (const float4*)(cT + ((size_t)srcb * HW + y0 * WW + x1) * CC);
    const float4* cd = (const float4*)(cT + ((size_t)srcb * HW + y1 * WW + x1) * CC);
    float4 A2 = ca[tid], B2 = cb[tid], C2 = cc[tid], D2 = cd[tid];
    u.x = wa * A2.x + wb * B2.x + wc * C2.x + wd * D2.x;
    u.y = wa * A2.y + wb * B2.y + wc * C2.y + wd * D2.y;
    u.z = wa * A2.z + wb * B2.z + wc * C2.z + wd * D2.z;
    u.w = wa * A2.w + wb * B2.w + wc * C2.w + wd * D2.w;
    ss2 = u.x * u.x + u.y * u.y + u.z * u.z + u.w * u.w;
  }
#pragma unroll
  for (int m = 1; m < 64; m <<= 1) ss2 += __shfl_xor(ss2, m);
  if (ln == 0) red[w] = ss2;
  __syncthreads();
  ss2 = red[0] + red[1];
  if (tid < 128) {
    float sc2 = 1.f / fmaxf(sqrtf(ss2), 1e-10f);
    bf4 oc = {__float2bfloat16(u.x * sc2), __float2bfloat16(u.y * sc2),
              __float2bfloat16(u.z * sc2), __float2bfloat16(u.w * sc2)};
    ((bf4*)(Cb + ((size_t)slot * NB * NP + (size_t)b * NP + p) * CC))[tid] = oc;
  }
}

// ---------------------------------------------------------------- fused corr
// Stage a 128x64 bf16 tile into LDS in MFMA-chunk order
// [sub(2)][kq(4)][row(128)] of 8-elem chunks, via global_load_lds width=16.
__device__ __forceinline__ void stage64(const __hip_bfloat16* __restrict__ src,
                                        int row0, int k0, int ld,
                                        bf16x8* buf, int tid) {
#pragma unroll
  for (int i = 0; i < 4; ++i) {
    int c = i * 256 + tid;  // chunk index = sub*512 + kq*128 + m
    int s = c >> 9, rem = c & 511;
    int kq = rem >> 7, m = rem & 127;
    const __hip_bfloat16* g = src + (size_t)(row0 + m) * ld + (k0 + s * 32 + kq * 8);
    __builtin_amdgcn_global_load_lds(
        (const __attribute__((address_space(1))) void*)g,
        (__attribute__((address_space(3))) void*)&buf[i * 256 + (tid & 192)],
        16, 0, 0);
  }
}

// grid (8,8,64): z = h*16 + b. Block 256 = 4 waves, each wave 64x64 (4x4 MFMA).
// Merged K-loop, BK=64: fd (K=768, 12 iters) and cd (K=512, first 8 iters)
// staged together -> up to 64 MFMA per barrier. 64 KB LDS, 2 blocks/CU
// (VGPR-capped anyway at 128 acc regs).
__global__ __launch_bounds__(256, 2) void corr_kernel(
    const __hip_bfloat16* __restrict__ Fb, const __hip_bfloat16* __restrict__ Cb,
    float* __restrict__ rowfd, float* __restrict__ rowrcd,
    float* __restrict__ cross) {
  __shared__ bf16x8 Afs[1024], Bfs[1024], Acs[1024], Bcs[1024];  // 64 KB

  int z = blockIdx.z;
  int h = z >> 4, bb = z & 15;
  int p0 = blockIdx.x * 128, q0 = blockIdx.y * 128;
  int tid = threadIdx.x, ln = tid & 63, w = tid >> 6;
  int wm = w >> 1, wn = w & 1, quad = ln >> 4, t16 = ln & 15;

  const __hip_bfloat16* Af = Fb + (size_t)bb * (NP * CF);
  const __hip_bfloat16* Bf = Fb + ((size_t)h * NB + bb) * (NP * CF);
  const __hip_bfloat16* Ac = Cb + (size_t)bb * (NP * CC);
  const __hip_bfloat16* Bc = Cb + ((size_t)h * NB + bb) * (NP * CC);

  f32x4 accf[4][4], accc[4][4];
#pragma unroll
  for (int i = 0; i < 4; ++i)
#pragma unroll
    for (int j = 0; j < 4; ++j) {
      accf[i][j] = (f32x4){0.f, 0.f, 0.f, 0.f};
      accc[i][j] = (f32x4){0.f, 0.f, 0.f, 0.f};
    }

  for (int kt = 0; kt < 12; ++kt) {
    stage64(Af, p0, kt * 64, CF, Afs, tid);
    stage64(Bf, q0, kt * 64, CF, Bfs, tid);
    if (kt < 8) {
      stage64(Ac, p0, kt * 64, CC, Acs, tid);
      stage64(Bc, q0, kt * 64, CC, Bcs, tid);
    }
    __syncthreads();
#pragma unroll
    for (int s = 0; s < 2; ++s) {
      bf16x8 a[4], b[4];
#pragma unroll
      for (int mi = 0; mi < 4; ++mi)
        a[mi] = Afs[s * 512 + quad * 128 + wm * 64 + mi * 16 + t16];
#pragma unroll
      for (int ni = 0; ni < 4; ++ni)
        b[ni] = Bfs[s * 512 + quad * 128 + wn * 64 + ni * 16 + t16];
#pragma unroll
      for (int mi = 0; mi < 4; ++mi)
#pragma unroll
        for (int ni = 0; ni < 4; ++ni)
          accf[mi][ni] = __builtin_amdgcn_mfma_f32_16x16x32_bf16(
              a[mi], b[ni], accf[mi][ni], 0, 0, 0);
    }
    if (kt < 8) {
#pragma unroll
      for (int s = 0; s < 2; ++s) {
        bf16x8 a[4], b[4];
#pragma unroll
        for (int mi = 0; mi < 4; ++mi)
          a[mi] = Acs[s * 512 + quad * 128 + wm * 64 + mi * 16 + t16];
#pragma unroll
        for (int ni = 0; ni < 4; ++ni)
          b[ni] = Bcs[s * 512 + quad * 128 + wn * 64 + ni * 16 + t16];
#pragma unroll
        for (int mi = 0; mi < 4; ++mi)
#pragma unroll
          for (int ni = 0; ni < 4; ++ni)
            accc[mi][ni] = __builtin_amdgcn_mfma_f32_16x16x32_bf16(
                a[mi], b[ni], accc[mi][ni], 0, 0, 0);
      }
    }
    __syncthreads();
  }

  // ---- epilogue: C/D layout row = quad*4 + reg, col = t16
  float cross_l = 0.f;
#pragma unroll
  for (int mi = 0; mi < 4; ++mi) {
#pragma unroll
    for (int r = 0; r < 4; ++r) {
      float sfd = 0.f, srw = 0.f;
#pragma unroll
      for (int ni = 0; ni < 4; ++ni) {
        float fd = accf[mi][ni][r];
        float cd = accc[mi][ni][r];
        float rc = fmaxf(cd, 0.f);
        sfd += fd;
        srw += rc;
        cross_l += rc * fd;
      }
#pragma unroll
      for (int m = 1; m < 16; m <<= 1) {
        sfd += __shfl_xor(sfd, m);
        srw += __shfl_xor(srw, m);
      }
      if (t16 == 0) {
        int p = p0 + wm * 64 + mi * 16 + quad * 4 + r;
        size_t idx = ((size_t)h * NB + bb) * NP + p;
        atomicAdd(&rowfd[idx], sfd);
        atomicAdd(&rowrcd[idx], srw);
      }
    }
  }
#pragma unroll
  for (int m = 1; m < 64; m <<= 1) cross_l += __shfl_xor(cross_l, m);
  float* crs = (float*)Afs;  // LDS reuse (all waves past last barrier)
  if (ln == 0) crs[w] = cross_l;
  __syncthreads();
  if (tid == 0) atomicAdd(&cross[h], crs[0] + crs[1] + crs[2] + crs[3]);
}

// ---------------------------------------------------------------- finalize
__global__ void finalize_partial(const float* __restrict__ rowfd,
                                 const float* __restrict__ rowrcd,
                                 const float* __restrict__ cross,
                                 float* __restrict__ losses) {
  __shared__ float r1[16], r2[16], r3[16];
  const float shifts[4] = {0.18f, 0.12f, 0.46f, 0.46f};
  int h = blockIdx.x, tid = threadIdx.x, w = tid >> 6, ln = tid & 63;
  float s1 = 0.f, s2 = 0.f, s3 = 0.f;
  for (int i = tid; i < NB * NP; i += 1024) {
    float a = rowfd[h * NB * NP + i];
    float c = rowrcd[h * NB * NP + i];
    s1 += a;
    s2 += c;
    s3 += a * c;
  }
#pragma unroll
  for (int m = 1; m < 64; m <<= 1) {
    s1 += __shfl_xor(s1, m);
    s2 += __shfl_xor(s2, m);
    s3 += __shfl_xor(s3, m);
  }
  if (ln == 0) { r1[w] = s1; r2[w] = s2; r3[w] = s3; }
  __syncthreads();
  if (tid == 0) {
    float Sfd = 0.f, Srcd = 0.f, Sdot = 0.f;
#pragma unroll
    for (int i = 0; i < 16; ++i) { Sfd += r1[i]; Srcd += r2[i]; Sdot += r3[i]; }
    losses[h] = -(cross[h] - Sdot * (1.0f / 1024.0f) +
                  (Sfd / NTOT - shifts[h]) * Srcd) / NTOT;
  }
}

__global__ void finalize_combine(const float* __restrict__ losses,
                                 float* __restrict__ out) {
  if (threadIdx.x == 0) {
    out[0] = losses[0];
    out[1] = losses[1];
    out[2] = 0.5f * (losses[2] + losses[3]);
  }
}

// ---------------------------------------------------------------- launch
extern "C" void kernel_launch(void* const* d_in, const int* in_sizes, int n_in,
                              void* d_out, int out_size, void* d_ws, size_t ws_size,
                              hipStream_t stream) {
  (void)in_sizes; (void)n_in; (void)out_size; (void)ws_size;
  const float* orig_feats = (const float*)d_in[0];
  const float* orig_feats_pos = (const float*)d_in[1];
  const float* orig_code = (const float*)d_in[4];
  const float* orig_code_pos = (const float*)d_in[5];
  const float* coords1 = (const float*)d_in[8];
  const float* coords2 = (const float*)d_in[9];
  const int* perms = (const int*)d_in[10];
  float* out = (float*)d_out;

  char* ws = (char*)d_ws;
  size_t off = 0;
  float* featsT = (float*)(ws + off); off += (size_t)NB * HW * CF * 4;
  float* codeT  = (float*)(ws + off); off += (size_t)NB * HW * CC * 4;
  __hip_bfloat16* Fb = (__hip_bfloat16*)(ws + off); off += (size_t)4 * NB * NP * CF * 2;
  __hip_bfloat16* Cb = (__hip_bfloat16*)(ws + off); off += (size_t)4 * NB * NP * CC * 2;
  float* rowfd  = (float*)(ws + off); off += (size_t)4 * NB * NP * 4;
  float* rowrcd = (float*)(ws + off); off += (size_t)4 * NB * NP * 4;
  float* cross  = (float*)(ws + off); off += 64;
  float* losses = (float*)(ws + off); off += 64;

  // zero accumulators (rowfd | rowrcd | cross | losses contiguous)
  (void)hipMemsetAsync(rowfd, 0, (size_t)4 * NB * NP * 4 * 2 + 128, stream);

  dim3 tb(32, 8);
  // pass 1: self tensors -> helper slots 0 (self@c1), 2,3 (neg@c2 permuted)
  transpose_kernel<<<dim3(25, 24, 16), tb, 0, stream>>>(orig_feats, featsT, CF);
  transpose_kernel<<<dim3(25, 16, 16), tb, 0, stream>>>(orig_code, codeT, CC);
  sample_norm_kernel<<<dim3(NP, NB, 3), 192, 0, stream>>>(
      featsT, codeT, coords1, coords2, perms, 0, Fb, Cb);
  // pass 2: pos tensors reuse transpose buffers -> slot 1 (pos@c2)
  transpose_kernel<<<dim3(25, 24, 16), tb, 0, stream>>>(orig_feats_pos, featsT, CF);
  transpose_kernel<<<dim3(25, 16, 16), tb, 0, stream>>>(orig_code_pos, codeT, CC);
  sample_norm_kernel<<<dim3(NP, NB, 1), 192, 0, stream>>>(
      featsT, codeT, coords1, coords2, perms, 1, Fb, Cb);

  corr_kernel<<<dim3(8, 8, 64), 256, 0, stream>>>(Fb, Cb, rowfd, rowrcd, cross);
  finalize_partial<<<4, 1024, 0, stream>>>(rowfd, rowrcd, cross, losses);
  finalize_combine<<<1, 64, 0, stream>>>(losses, out);
}

// Round 3
// 672.527 us; speedup vs baseline: 1.3260x; 1.1160x over previous
//
#include <hip/hip_runtime.h>
#include <hip/hip_bf16.h>

#define NB 16
#define NP 1024
#define CF 768
#define CC 512
#define HH 28
#define WW 28
#define HW 784
#define NTOT 16777216.0f  // 16*1024*1024

typedef short bf16x8 __attribute__((ext_vector_type(8)));
typedef float f32x4 __attribute__((ext_vector_type(4)));
struct __align__(8) bf4 { __hip_bfloat16 a, b, c, d; };

// Swizzled global layout for the GEMM operands ("supertiles"):
//   feats: [slot(4)][b(16)][kt(12)][pt(8)] x 1024 chunks of 16B,
//   code : [slot(4)][b(16)][kt(8) ][pt(8)] x 1024 chunks of 16B,
// chunk index within supertile = r*128 + m  (r = s*4+kq in [0,8), m = p&127),
// chunk payload = 8 bf16 = channels [kt*64 + r*8 .. +8) of row p.
// This is EXACTLY the LDS image corr_kernel's MFMA ds_reads want, so the
// global->LDS staging is a fully contiguous 16 KB stream per tile.

// ---------------------------------------------------------------- transpose
// (B, C, HW) f32 -> (B, HW, C) f32, LDS-tiled, coalesced both sides.
__global__ void transpose_kernel(const float* __restrict__ in,
                                 float* __restrict__ out, int C) {
  __shared__ float tile[32][33];
  int p0 = blockIdx.x * 32, c0 = blockIdx.y * 32, b = blockIdx.z;
  int tx = threadIdx.x, ty = threadIdx.y;
  const float* ib = in + (size_t)b * C * HW;
  float* ob = out + (size_t)b * HW * C;
#pragma unroll
  for (int i = 0; i < 32; i += 8) {
    int c = c0 + ty + i, p = p0 + tx;
    if (p < HW) tile[ty + i][tx] = ib[(size_t)c * HW + p];
  }
  __syncthreads();
#pragma unroll
  for (int i = 0; i < 32; i += 8) {
    int p = p0 + ty + i, c = c0 + tx;
    if (p < HW) ob[(size_t)p * C + c] = tile[tx][ty + i];
  }
}

// ---------------------------------------------------------------- sampling
// Block = 192 threads, one block per (position, batch, variant). float4
// gathers from channel-last tensors; L2-normalize; scatter-store bf16 halves
// of 16B chunks into the supertile layout above.
__global__ void sample_norm_kernel(const float* __restrict__ fT,
                                   const float* __restrict__ cT,
                                   const float* __restrict__ coords1,
                                   const float* __restrict__ coords2,
                                   const int* __restrict__ perms, int pass,
                                   __hip_bfloat16* __restrict__ Fb,
                                   __hip_bfloat16* __restrict__ Cb) {
  __shared__ float red[4];
  int p = blockIdx.x, b = blockIdx.y, z = blockIdx.z;
  int tid = threadIdx.x, w = tid >> 6, ln = tid & 63;

  const float* coords;
  int srcb, slot;
  if (pass == 0) {
    if (z == 0)      { coords = coords1; srcb = b;             slot = 0; }
    else if (z == 1) { coords = coords2; srcb = perms[b];      slot = 2; }
    else             { coords = coords2; srcb = perms[16 + b]; slot = 3; }
  } else             { coords = coords2; srcb = b;             slot = 1; }

  float cx = coords[((size_t)b * NP + p) * 2 + 0];
  float cy = coords[((size_t)b * NP + p) * 2 + 1];
  float x = cx * (WW - 1), y = cy * (HH - 1);   // (c*2-1 +1)*0.5*(W-1)
  float x0f = floorf(x), y0f = floorf(y);
  float wx = x - x0f, wy = y - y0f;
  int x0 = min(max((int)x0f, 0), WW - 1);
  int x1 = min(max((int)x0f + 1, 0), WW - 1);
  int y0 = min(max((int)y0f, 0), HH - 1);
  int y1 = min(max((int)y0f + 1, 0), HH - 1);
  float wa = (1.f - wx) * (1.f - wy);
  float wb = (1.f - wx) * wy;
  float wc = wx * (1.f - wy);
  float wd = wx * wy;

  int kc = tid >> 1, half = tid & 1;  // k-chunk, which 8B half of the chunk
  int pt = p >> 7, m = p & 127;

  // -------- feats: 192 threads x float4 = 768 channels
  const float4* ra = (const float4*)(fT + ((size_t)srcb * HW + y0 * WW + x0) * CF);
  const float4* rb = (const float4*)(fT + ((size_t)srcb * HW + y1 * WW + x0) * CF);
  const float4* rc = (const float4*)(fT + ((size_t)srcb * HW + y0 * WW + x1) * CF);
  const float4* rd = (const float4*)(fT + ((size_t)srcb * HW + y1 * WW + x1) * CF);
  float4 A = ra[tid], Bv = rb[tid], Cv = rc[tid], D = rd[tid];
  float4 v;
  v.x = wa * A.x + wb * Bv.x + wc * Cv.x + wd * D.x;
  v.y = wa * A.y + wb * Bv.y + wc * Cv.y + wd * D.y;
  v.z = wa * A.z + wb * Bv.z + wc * Cv.z + wd * D.z;
  v.w = wa * A.w + wb * Bv.w + wc * Cv.w + wd * D.w;
  float ss = v.x * v.x + v.y * v.y + v.z * v.z + v.w * v.w;
#pragma unroll
  for (int mm = 1; mm < 64; mm <<= 1) ss += __shfl_xor(ss, mm);
  if (ln == 0) red[w] = ss;
  __syncthreads();
  ss = red[0] + red[1] + red[2];
  float sc = 1.f / fmaxf(sqrtf(ss), 1e-10f);
  bf4 of = {__float2bfloat16(v.x * sc), __float2bfloat16(v.y * sc),
            __float2bfloat16(v.z * sc), __float2bfloat16(v.w * sc)};
  {
    int kt = kc >> 3, r = kc & 7;
    size_t chunk = ((((size_t)slot * NB + b) * 12 + kt) * 8 + pt) * 1024 + r * 128 + m;
    *(bf4*)((char*)Fb + chunk * 16 + half * 8) = of;
  }
  __syncthreads();  // red[] reuse

  // -------- code: threads 0..127 x float4 = 512 channels
  float4 u = {0.f, 0.f, 0.f, 0.f};
  float ss2 = 0.f;
  if (tid < 128) {
    const float4* ca = (const float4*)(cT + ((size_t)srcb * HW + y0 * WW + x0) * CC);
    const float4* cb = (const float4*)(cT + ((size_t)srcb * HW + y1 * WW + x0) * CC);
    const float4* cc = (const float4*)(cT + ((size_t)srcb * HW + y0 * WW + x1) * CC);
    const float4* cd = (const float4*)(cT + ((size_t)srcb * HW + y1 * WW + x1) * CC);
    float4 A2 = ca[tid], B2 = cb[tid], C2 = cc[tid], D2 = cd[tid];
    u.x = wa * A2.x + wb * B2.x + wc * C2.x + wd * D2.x;
    u.y = wa * A2.y + wb * B2.y + wc * C2.y + wd * D2.y;
    u.z = wa * A2.z + wb * B2.z + wc * C2.z + wd * D2.z;
    u.w = wa * A2.w + wb * B2.w + wc * C2.w + wd * D2.w;
    ss2 = u.x * u.x + u.y * u.y + u.z * u.z + u.w * u.w;
  }
#pragma unroll
  for (int mm = 1; mm < 64; mm <<= 1) ss2 += __shfl_xor(ss2, mm);
  if (ln == 0) red[w] = ss2;
  __syncthreads();
  ss2 = red[0] + red[1];
  if (tid < 128) {
    float sc2 = 1.f / fmaxf(sqrtf(ss2), 1e-10f);
    bf4 oc = {__float2bfloat16(u.x * sc2), __float2bfloat16(u.y * sc2),
              __float2bfloat16(u.z * sc2), __float2bfloat16(u.w * sc2)};
    int kt = kc >> 3, r = kc & 7;
    size_t chunk = ((((size_t)slot * NB + b) * 8 + kt) * 8 + pt) * 1024 + r * 128 + m;
    *(bf4*)((char*)Cb + chunk * 16 + half * 8) = oc;
  }
}

// ---------------------------------------------------------------- fused corr
// Stage one 16 KB supertile (contiguous in global!) into LDS; chunk c goes to
// LDS slot c -> image identical to R2's conflict-free layout.
__device__ __forceinline__ void stage_sup(const __hip_bfloat16* __restrict__ st,
                                          bf16x8* buf, int tid) {
#pragma unroll
  for (int i = 0; i < 4; ++i) {
    const __hip_bfloat16* g = st + (size_t)(i * 256 + tid) * 8;
    __builtin_amdgcn_global_load_lds(
        (const __attribute__((address_space(1))) void*)g,
        (__attribute__((address_space(3))) void*)&buf[i * 256 + (tid & 192)],
        16, 0, 0);
  }
}

// grid (8,8,64): z = h*16 + b. Block 256 = 4 waves, each wave 64x64 (4x4 MFMA).
// Merged K-loop, BK=64: fd (K=768, 12 iters) and cd (K=512, first 8 iters).
__global__ __launch_bounds__(256, 2) void corr_kernel(
    const __hip_bfloat16* __restrict__ Fb, const __hip_bfloat16* __restrict__ Cb,
    float* __restrict__ rowfd, float* __restrict__ rowrcd,
    float* __restrict__ cross) {
  __shared__ bf16x8 Afs[1024], Bfs[1024], Acs[1024], Bcs[1024];  // 64 KB

  int z = blockIdx.z;
  int h = z >> 4, bb = z & 15;
  int bx = blockIdx.x, by = blockIdx.y;
  int p0 = bx * 128;
  int tid = threadIdx.x, ln = tid & 63, w = tid >> 6;
  int wm = w >> 1, wn = w & 1, quad = ln >> 4, t16 = ln & 15;

  // supertile bases (in bf16 elements = chunk_index * 8)
  const __hip_bfloat16* AfB = Fb + ((((size_t)0 * NB + bb) * 12) * 8 + bx) * 8192;
  const __hip_bfloat16* BfB = Fb + ((((size_t)h * NB + bb) * 12) * 8 + by) * 8192;
  const __hip_bfloat16* AcB = Cb + ((((size_t)0 * NB + bb) * 8) * 8 + bx) * 8192;
  const __hip_bfloat16* BcB = Cb + ((((size_t)h * NB + bb) * 8) * 8 + by) * 8192;
  const size_t KTSTR = (size_t)8 * 8192;  // one kt step = 8 supertiles

  f32x4 accf[4][4], accc[4][4];
#pragma unroll
  for (int i = 0; i < 4; ++i)
#pragma unroll
    for (int j = 0; j < 4; ++j) {
      accf[i][j] = (f32x4){0.f, 0.f, 0.f, 0.f};
      accc[i][j] = (f32x4){0.f, 0.f, 0.f, 0.f};
    }

  for (int kt = 0; kt < 12; ++kt) {
    stage_sup(AfB + kt * KTSTR, Afs, tid);
    stage_sup(BfB + kt * KTSTR, Bfs, tid);
    if (kt < 8) {
      stage_sup(AcB + kt * KTSTR, Acs, tid);
      stage_sup(BcB + kt * KTSTR, Bcs, tid);
    }
    __syncthreads();
#pragma unroll
    for (int s = 0; s < 2; ++s) {
      bf16x8 a[4], b[4];
#pragma unroll
      for (int mi = 0; mi < 4; ++mi)
        a[mi] = Afs[s * 512 + quad * 128 + wm * 64 + mi * 16 + t16];
#pragma unroll
      for (int ni = 0; ni < 4; ++ni)
        b[ni] = Bfs[s * 512 + quad * 128 + wn * 64 + ni * 16 + t16];
#pragma unroll
      for (int mi = 0; mi < 4; ++mi)
#pragma unroll
        for (int ni = 0; ni < 4; ++ni)
          accf[mi][ni] = __builtin_amdgcn_mfma_f32_16x16x32_bf16(
              a[mi], b[ni], accf[mi][ni], 0, 0, 0);
    }
    if (kt < 8) {
#pragma unroll
      for (int s = 0; s < 2; ++s) {
        bf16x8 a[4], b[4];
#pragma unroll
        for (int mi = 0; mi < 4; ++mi)
          a[mi] = Acs[s * 512 + quad * 128 + wm * 64 + mi * 16 + t16];
#pragma unroll
        for (int ni = 0; ni < 4; ++ni)
          b[ni] = Bcs[s * 512 + quad * 128 + wn * 64 + ni * 16 + t16];
#pragma unroll
        for (int mi = 0; mi < 4; ++mi)
#pragma unroll
          for (int ni = 0; ni < 4; ++ni)
            accc[mi][ni] = __builtin_amdgcn_mfma_f32_16x16x32_bf16(
                a[mi], b[ni], accc[mi][ni], 0, 0, 0);
      }
    }
    __syncthreads();
  }

  // ---- epilogue: C/D layout row = quad*4 + reg, col = t16
  float cross_l = 0.f;
#pragma unroll
  for (int mi = 0; mi < 4; ++mi) {
#pragma unroll
    for (int r = 0; r < 4; ++r) {
      float sfd = 0.f, srw = 0.f;
#pragma unroll
      for (int ni = 0; ni < 4; ++ni) {
        float fd = accf[mi][ni][r];
        float cd = accc[mi][ni][r];
        float rc = fmaxf(cd, 0.f);
        sfd += fd;
        srw += rc;
        cross_l += rc * fd;
      }
#pragma unroll
      for (int mm = 1; mm < 16; mm <<= 1) {
        sfd += __shfl_xor(sfd, mm);
        srw += __shfl_xor(srw, mm);
      }
      if (t16 == 0) {
        int p = p0 + wm * 64 + mi * 16 + quad * 4 + r;
        size_t idx = ((size_t)h * NB + bb) * NP + p;
        atomicAdd(&rowfd[idx], sfd);
        atomicAdd(&rowrcd[idx], srw);
      }
    }
  }
#pragma unroll
  for (int mm = 1; mm < 64; mm <<= 1) cross_l += __shfl_xor(cross_l, mm);
  float* crs = (float*)Afs;  // LDS reuse (all waves past last barrier)
  if (ln == 0) crs[w] = cross_l;
  __syncthreads();
  if (tid == 0) atomicAdd(&cross[h], crs[0] + crs[1] + crs[2] + crs[3]);
}

// ---------------------------------------------------------------- finalize
__global__ void finalize_partial(const float* __restrict__ rowfd,
                                 const float* __restrict__ rowrcd,
                                 const float* __restrict__ cross,
                                 float* __restrict__ losses) {
  __shared__ float r1[16], r2[16], r3[16];
  const float shifts[4] = {0.18f, 0.12f, 0.46f, 0.46f};
  int h = blockIdx.x, tid = threadIdx.x, w = tid >> 6, ln = tid & 63;
  float s1 = 0.f, s2 = 0.f, s3 = 0.f;
  for (int i = tid; i < NB * NP; i += 1024) {
    float a = rowfd[h * NB * NP + i];
    float c = rowrcd[h * NB * NP + i];
    s1 += a;
    s2 += c;
    s3 += a * c;
  }
#pragma unroll
  for (int mm = 1; mm < 64; mm <<= 1) {
    s1 += __shfl_xor(s1, mm);
    s2 += __shfl_xor(s2, mm);
    s3 += __shfl_xor(s3, mm);
  }
  if (ln == 0) { r1[w] = s1; r2[w] = s2; r3[w] = s3; }
  __syncthreads();
  if (tid == 0) {
    float Sfd = 0.f, Srcd = 0.f, Sdot = 0.f;
#pragma unroll
    for (int i = 0; i < 16; ++i) { Sfd += r1[i]; Srcd += r2[i]; Sdot += r3[i]; }
    losses[h] = -(cross[h] - Sdot * (1.0f / 1024.0f) +
                  (Sfd / NTOT - shifts[h]) * Srcd) / NTOT;
  }
}

__global__ void finalize_combine(const float* __restrict__ losses,
                                 float* __restrict__ out) {
  if (threadIdx.x == 0) {
    out[0] = losses[0];
    out[1] = losses[1];
    out[2] = 0.5f * (losses[2] + losses[3]);
  }
}

// ---------------------------------------------------------------- launch
extern "C" void kernel_launch(void* const* d_in, const int* in_sizes, int n_in,
                              void* d_out, int out_size, void* d_ws, size_t ws_size,
                              hipStream_t stream) {
  (void)in_sizes; (void)n_in; (void)out_size; (void)ws_size;
  const float* orig_feats = (const float*)d_in[0];
  const float* orig_feats_pos = (const float*)d_in[1];
  const float* orig_code = (const float*)d_in[4];
  const float* orig_code_pos = (const float*)d_in[5];
  const float* coords1 = (const float*)d_in[8];
  const float* coords2 = (const float*)d_in[9];
  const int* perms = (const int*)d_in[10];
  float* out = (float*)d_out;

  char* ws = (char*)d_ws;
  size_t off = 0;
  float* featsT = (float*)(ws + off); off += (size_t)NB * HW * CF * 4;
  float* codeT  = (float*)(ws + off); off += (size_t)NB * HW * CC * 4;
  __hip_bfloat16* Fb = (__hip_bfloat16*)(ws + off); off += (size_t)4 * NB * NP * CF * 2;
  __hip_bfloat16* Cb = (__hip_bfloat16*)(ws + off); off += (size_t)4 * NB * NP * CC * 2;
  float* rowfd  = (float*)(ws + off); off += (size_t)4 * NB * NP * 4;
  float* rowrcd = (float*)(ws + off); off += (size_t)4 * NB * NP * 4;
  float* cross  = (float*)(ws + off); off += 64;
  float* losses = (float*)(ws + off); off += 64;

  // zero accumulators (rowfd | rowrcd | cross | losses contiguous)
  (void)hipMemsetAsync(rowfd, 0, (size_t)4 * NB * NP * 4 * 2 + 128, stream);

  dim3 tb(32, 8);
  // pass 1: self tensors -> helper slots 0 (self@c1), 2,3 (neg@c2 permuted)
  transpose_kernel<<<dim3(25, 24, 16), tb, 0, stream>>>(orig_feats, featsT, CF);
  transpose_kernel<<<dim3(25, 16, 16), tb, 0, stream>>>(orig_code, codeT, CC);
  sample_norm_kernel<<<dim3(NP, NB, 3), 192, 0, stream>>>(
      featsT, codeT, coords1, coords2, perms, 0, Fb, Cb);
  // pass 2: pos tensors reuse transpose buffers -> slot 1 (pos@c2)
  transpose_kernel<<<dim3(25, 24, 16), tb, 0, stream>>>(orig_feats_pos, featsT, CF);
  transpose_kernel<<<dim3(25, 16, 16), tb, 0, stream>>>(orig_code_pos, codeT, CC);
  sample_norm_kernel<<<dim3(NP, NB, 1), 192, 0, stream>>>(
      featsT, codeT, coords1, coords2, perms, 1, Fb, Cb);

  corr_kernel<<<dim3(8, 8, 64), 256, 0, stream>>>(Fb, Cb, rowfd, rowrcd, cross);
  finalize_partial<<<4, 1024, 0, stream>>>(rowfd, rowrcd, cross, losses);
  finalize_combine<<<1, 64, 0, stream>>>(losses, out);
}

// Round 4
// 635.126 us; speedup vs baseline: 1.4041x; 1.0589x over previous
//
#include <hip/hip_runtime.h>
#include <hip/hip_bf16.h>

#define NB 16
#define NP 1024
#define CF 768
#define CC 512
#define HH 28
#define WW 28
#define HW 784
#define NTOT 16777216.0f  // 16*1024*1024

typedef short bf16x8 __attribute__((ext_vector_type(8)));
typedef float f32x4 __attribute__((ext_vector_type(4)));
struct __align__(8) bf4 { __hip_bfloat16 a, b, c, d; };

// Supertile layout (UNSCALED bf16; norms applied in corr epilogue):
//   feats: [slot(4)][b(16)][kt(12)][pt(8)] x 1024 chunks of 16B,
//   code : [slot(4)][b(16)][kt(8) ][pt(8)] x 1024 chunks of 16B,
// chunk index = r*128 + m (r in [0,8), m = p&127), payload = 8 bf16 =
// channels [kt*64 + r*8 .. +8) of position row p. Identical to the LDS image
// corr_kernel's MFMA ds_reads consume -> staging is a contiguous 16 KB stream.
// Norm scales: scF/scC [slot][b][p] f32, applied as rank-1 diag in epilogue
// (relu commutes with positive scales).

// ---------------------------------------------------------------- transpose
__global__ void transpose_kernel(const float* __restrict__ in,
                                 float* __restrict__ out, int C) {
  __shared__ float tile[32][33];
  int p0 = blockIdx.x * 32, c0 = blockIdx.y * 32, b = blockIdx.z;
  int tx = threadIdx.x, ty = threadIdx.y;
  const float* ib = in + (size_t)b * C * HW;
  float* ob = out + (size_t)b * HW * C;
#pragma unroll
  for (int i = 0; i < 32; i += 8) {
    int c = c0 + ty + i, p = p0 + tx;
    if (p < HW) tile[ty + i][tx] = ib[(size_t)c * HW + p];
  }
  __syncthreads();
#pragma unroll
  for (int i = 0; i < 32; i += 8) {
    int p = p0 + ty + i, c = c0 + tx;
    if (p < HW) ob[(size_t)p * C + c] = tile[tx][ty + i];
  }
}

// ---------------------------------------------------------------- sampling
// Block = 256 threads = 16 groups of 16 lanes; handles 64 positions of one
// (slot, batch). Per kt-slice (64 ch): group g computes positions j*16+g,
// lane l reads float4 of 4 corners (coalesced 256B segments), combines,
// accumulates ssq (f32), stores UNSCALED bf16 into LDS supertile tile,
// then block flushes 8 KB contiguous to global. After all kts: group-reduce
// ssq -> write reciprocal-norm scale.
__global__ __launch_bounds__(256) void sample_pack_kernel(
    const float* __restrict__ fT, const float* __restrict__ cT,
    const float* __restrict__ coords1, const float* __restrict__ coords2,
    const int* __restrict__ perms, int pass,
    __hip_bfloat16* __restrict__ Fb, __hip_bfloat16* __restrict__ Cb,
    float* __restrict__ scF, float* __restrict__ scC) {
  __shared__ int offs[4][64];
  __shared__ float wts[4][64];
  __shared__ char tile[8320];  // 512 chunks*16B + 16B pad per r

  int bb = blockIdx.y, zz = blockIdx.z;
  int tid = threadIdx.x;
  int p0 = blockIdx.x * 64;
  int pt = blockIdx.x >> 1, mh = blockIdx.x & 1;

  const float* coords; int srcb, slot;
  if (pass == 0) {
    if (zz == 0)      { coords = coords1; srcb = bb;             slot = 0; }
    else if (zz == 1) { coords = coords2; srcb = perms[bb];      slot = 2; }
    else              { coords = coords2; srcb = perms[16 + bb]; slot = 3; }
  } else              { coords = coords2; srcb = bb;             slot = 1; }

  if (tid < 64) {
    int p = p0 + tid;
    float cx = coords[((size_t)bb * NP + p) * 2 + 0];
    float cy = coords[((size_t)bb * NP + p) * 2 + 1];
    float x = cx * (WW - 1), y = cy * (HH - 1);  // (c*2-1 +1)*0.5*(W-1)
    float x0f = floorf(x), y0f = floorf(y);
    float wx = x - x0f, wy = y - y0f;
    int x0 = min(max((int)x0f, 0), WW - 1);
    int x1 = min(max((int)x0f + 1, 0), WW - 1);
    int y0 = min(max((int)y0f, 0), HH - 1);
    int y1 = min(max((int)y0f + 1, 0), HH - 1);
    offs[0][tid] = y0 * WW + x0;
    offs[1][tid] = y1 * WW + x0;
    offs[2][tid] = y0 * WW + x1;
    offs[3][tid] = y1 * WW + x1;
    wts[0][tid] = (1.f - wx) * (1.f - wy);
    wts[1][tid] = (1.f - wx) * wy;
    wts[2][tid] = wx * (1.f - wy);
    wts[3][tid] = wx * wy;
  }
  __syncthreads();

  int gid = tid >> 4, l = tid & 15;
  int r = l >> 1, half = l & 1;

  // ---------------- feats (12 kt-slices)
  {
    const float* base = fT + (size_t)srcb * HW * CF;
    float ssq[4] = {0.f, 0.f, 0.f, 0.f};
    for (int kt = 0; kt < 12; ++kt) {
#pragma unroll
      for (int j = 0; j < 4; ++j) {
        int m = j * 16 + gid;
        int ch = kt * 64 + l * 4;
        float4 v = {0.f, 0.f, 0.f, 0.f};
#pragma unroll
        for (int c = 0; c < 4; ++c) {
          const float4 t4 = *(const float4*)(base + (size_t)offs[c][m] * CF + ch);
          float wv = wts[c][m];
          v.x += wv * t4.x; v.y += wv * t4.y; v.z += wv * t4.z; v.w += wv * t4.w;
        }
        ssq[j] += v.x * v.x + v.y * v.y + v.z * v.z + v.w * v.w;
        bf4 o = {__float2bfloat16(v.x), __float2bfloat16(v.y),
                 __float2bfloat16(v.z), __float2bfloat16(v.w)};
        int cl = r * 64 + m;
        *(bf4*)(tile + cl * 16 + r * 16 + half * 8) = o;
      }
      __syncthreads();
      char* gbase = (char*)Fb +
          (((((size_t)slot * NB + bb) * 12 + kt) * 8 + pt) * 1024 + (size_t)mh * 64) * 16;
#pragma unroll
      for (int jj = 0; jj < 2; ++jj) {
        int cl = jj * 256 + tid;
        int rr = cl >> 6, mi = cl & 63;
        float4 val = *(const float4*)(tile + cl * 16 + rr * 16);
        *(float4*)(gbase + (size_t)(rr * 128 + mi) * 16) = val;
      }
      __syncthreads();
    }
#pragma unroll
    for (int j = 0; j < 4; ++j) {
#pragma unroll
      for (int mm = 1; mm < 16; mm <<= 1) ssq[j] += __shfl_xor(ssq[j], mm);
    }
    if (l == 0) {
#pragma unroll
      for (int j = 0; j < 4; ++j) {
        int p = p0 + j * 16 + gid;
        scF[((size_t)slot * NB + bb) * NP + p] = 1.f / fmaxf(sqrtf(ssq[j]), 1e-10f);
      }
    }
  }

  // ---------------- code (8 kt-slices)
  {
    const float* base = cT + (size_t)srcb * HW * CC;
    float ssq[4] = {0.f, 0.f, 0.f, 0.f};
    for (int kt = 0; kt < 8; ++kt) {
#pragma unroll
      for (int j = 0; j < 4; ++j) {
        int m = j * 16 + gid;
        int ch = kt * 64 + l * 4;
        float4 v = {0.f, 0.f, 0.f, 0.f};
#pragma unroll
        for (int c = 0; c < 4; ++c) {
          const float4 t4 = *(const float4*)(base + (size_t)offs[c][m] * CC + ch);
          float wv = wts[c][m];
          v.x += wv * t4.x; v.y += wv * t4.y; v.z += wv * t4.z; v.w += wv * t4.w;
        }
        ssq[j] += v.x * v.x + v.y * v.y + v.z * v.z + v.w * v.w;
        bf4 o = {__float2bfloat16(v.x), __float2bfloat16(v.y),
                 __float2bfloat16(v.z), __float2bfloat16(v.w)};
        int cl = r * 64 + m;
        *(bf4*)(tile + cl * 16 + r * 16 + half * 8) = o;
      }
      __syncthreads();
      char* gbase = (char*)Cb +
          (((((size_t)slot * NB + bb) * 8 + kt) * 8 + pt) * 1024 + (size_t)mh * 64) * 16;
#pragma unroll
      for (int jj = 0; jj < 2; ++jj) {
        int cl = jj * 256 + tid;
        int rr = cl >> 6, mi = cl & 63;
        float4 val = *(const float4*)(tile + cl * 16 + rr * 16);
        *(float4*)(gbase + (size_t)(rr * 128 + mi) * 16) = val;
      }
      __syncthreads();
    }
#pragma unroll
    for (int j = 0; j < 4; ++j) {
#pragma unroll
      for (int mm = 1; mm < 16; mm <<= 1) ssq[j] += __shfl_xor(ssq[j], mm);
    }
    if (l == 0) {
#pragma unroll
      for (int j = 0; j < 4; ++j) {
        int p = p0 + j * 16 + gid;
        scC[((size_t)slot * NB + bb) * NP + p] = 1.f / fmaxf(sqrtf(ssq[j]), 1e-10f);
      }
    }
  }
}

// ---------------------------------------------------------------- fused corr
__device__ __forceinline__ void stage_sup(const __hip_bfloat16* __restrict__ st,
                                          bf16x8* buf, int tid) {
#pragma unroll
  for (int i = 0; i < 4; ++i) {
    const __hip_bfloat16* g = st + (size_t)(i * 256 + tid) * 8;
    __builtin_amdgcn_global_load_lds(
        (const __attribute__((address_space(1))) void*)g,
        (__attribute__((address_space(3))) void*)&buf[i * 256 + (tid & 192)],
        16, 0, 0);
  }
}

// grid 4096 linear, decoded so id%8 == z%8 and one z's 64 tile-blocks are
// temporally co-resident per XCD (L2 working set ~5 MB streamed per kt).
// Block 256 = 4 waves, each wave 64x64 (4x4 MFMA). Merged K-loop, BK=64.
// Epilogue applies rank-1 norm scales before reductions.
__global__ __launch_bounds__(256, 2) void corr_kernel(
    const __hip_bfloat16* __restrict__ Fb, const __hip_bfloat16* __restrict__ Cb,
    const float* __restrict__ scF, const float* __restrict__ scC,
    float* __restrict__ rowfd, float* __restrict__ rowrcd,
    float* __restrict__ cross) {
  __shared__ bf16x8 Afs[1024], Bfs[1024], Acs[1024], Bcs[1024];  // 64 KB

  int id = blockIdx.x;
  int zl = id & 7, q = id >> 3;
  int bx = q & 7, by = (q >> 3) & 7, zh = q >> 6;
  int z = zh * 8 + zl;
  int h = z >> 4, bb = z & 15;
  int p0 = bx * 128, q0 = by * 128;
  int tid = threadIdx.x, ln = tid & 63, w = tid >> 6;
  int wm = w >> 1, wn = w & 1, quad = ln >> 4, t16 = ln & 15;

  const __hip_bfloat16* AfB = Fb + (((size_t)bb * 12) * 8 + bx) * 8192;
  const __hip_bfloat16* BfB = Fb + ((((size_t)h * NB + bb) * 12) * 8 + by) * 8192;
  const __hip_bfloat16* AcB = Cb + (((size_t)bb * 8) * 8 + bx) * 8192;
  const __hip_bfloat16* BcB = Cb + ((((size_t)h * NB + bb) * 8) * 8 + by) * 8192;
  const size_t KTSTR = (size_t)8 * 8192;

  f32x4 accf[4][4], accc[4][4];
#pragma unroll
  for (int i = 0; i < 4; ++i)
#pragma unroll
    for (int j = 0; j < 4; ++j) {
      accf[i][j] = (f32x4){0.f, 0.f, 0.f, 0.f};
      accc[i][j] = (f32x4){0.f, 0.f, 0.f, 0.f};
    }

  for (int kt = 0; kt < 12; ++kt) {
    stage_sup(AfB + kt * KTSTR, Afs, tid);
    stage_sup(BfB + kt * KTSTR, Bfs, tid);
    if (kt < 8) {
      stage_sup(AcB + kt * KTSTR, Acs, tid);
      stage_sup(BcB + kt * KTSTR, Bcs, tid);
    }
    __syncthreads();
#pragma unroll
    for (int s = 0; s < 2; ++s) {
      bf16x8 a[4], b[4];
#pragma unroll
      for (int mi = 0; mi < 4; ++mi)
        a[mi] = Afs[s * 512 + quad * 128 + wm * 64 + mi * 16 + t16];
#pragma unroll
      for (int ni = 0; ni < 4; ++ni)
        b[ni] = Bfs[s * 512 + quad * 128 + wn * 64 + ni * 16 + t16];
#pragma unroll
      for (int mi = 0; mi < 4; ++mi)
#pragma unroll
        for (int ni = 0; ni < 4; ++ni)
          accf[mi][ni] = __builtin_amdgcn_mfma_f32_16x16x32_bf16(
              a[mi], b[ni], accf[mi][ni], 0, 0, 0);
    }
    if (kt < 8) {
#pragma unroll
      for (int s = 0; s < 2; ++s) {
        bf16x8 a[4], b[4];
#pragma unroll
        for (int mi = 0; mi < 4; ++mi)
          a[mi] = Acs[s * 512 + quad * 128 + wm * 64 + mi * 16 + t16];
#pragma unroll
        for (int ni = 0; ni < 4; ++ni)
          b[ni] = Bcs[s * 512 + quad * 128 + wn * 64 + ni * 16 + t16];
#pragma unroll
        for (int mi = 0; mi < 4; ++mi)
#pragma unroll
          for (int ni = 0; ni < 4; ++ni)
            accc[mi][ni] = __builtin_amdgcn_mfma_f32_16x16x32_bf16(
                a[mi], b[ni], accc[mi][ni], 0, 0, 0);
      }
    }
    __syncthreads();
  }

  // ---- stage norm scales into LDS (reuse Afs)
  float* sm = (float*)Afs;
  {
    const float* s0 = scF + (size_t)bb * NP;
    const float* s1 = scF + ((size_t)h * NB + bb) * NP;
    const float* s2 = scC + (size_t)bb * NP;
    const float* s3 = scC + ((size_t)h * NB + bb) * NP;
    if (tid < 128) {
      sm[tid] = s0[p0 + tid];
      sm[256 + tid] = s2[p0 + tid];
    } else {
      int u = tid - 128;
      sm[128 + u] = s1[q0 + u];
      sm[384 + u] = s3[q0 + u];
    }
  }
  __syncthreads();

  // ---- epilogue: C/D layout row = quad*4 + reg, col = t16; apply scales
  float sbf[4], sbc[4];
#pragma unroll
  for (int ni = 0; ni < 4; ++ni) {
    int qq = wn * 64 + ni * 16 + t16;
    sbf[ni] = sm[128 + qq];
    sbc[ni] = sm[384 + qq];
  }
  float cross_l = 0.f;
#pragma unroll
  for (int mi = 0; mi < 4; ++mi) {
#pragma unroll
    for (int r = 0; r < 4; ++r) {
      int pl = wm * 64 + mi * 16 + quad * 4 + r;
      float saf = sm[pl], sac = sm[256 + pl];
      float sfd = 0.f, srw = 0.f;
#pragma unroll
      for (int ni = 0; ni < 4; ++ni) {
        float fd = accf[mi][ni][r] * (saf * sbf[ni]);
        float cd = accc[mi][ni][r] * (sac * sbc[ni]);
        float rc = fmaxf(cd, 0.f);
        sfd += fd;
        srw += rc;
        cross_l += rc * fd;
      }
#pragma unroll
      for (int mm = 1; mm < 16; mm <<= 1) {
        sfd += __shfl_xor(sfd, mm);
        srw += __shfl_xor(srw, mm);
      }
      if (t16 == 0) {
        int p = p0 + pl;
        size_t idx = ((size_t)h * NB + bb) * NP + p;
        atomicAdd(&rowfd[idx], sfd);
        atomicAdd(&rowrcd[idx], srw);
      }
    }
  }
#pragma unroll
  for (int mm = 1; mm < 64; mm <<= 1) cross_l += __shfl_xor(cross_l, mm);
  float* crs = (float*)Bfs;
  if (ln == 0) crs[w] = cross_l;
  __syncthreads();
  if (tid == 0) atomicAdd(&cross[h], crs[0] + crs[1] + crs[2] + crs[3]);
}

// ---------------------------------------------------------------- finalize
__global__ void finalize_partial(const float* __restrict__ rowfd,
                                 const float* __restrict__ rowrcd,
                                 const float* __restrict__ cross,
                                 float* __restrict__ losses) {
  __shared__ float r1[16], r2[16], r3[16];
  const float shifts[4] = {0.18f, 0.12f, 0.46f, 0.46f};
  int h = blockIdx.x, tid = threadIdx.x, w = tid >> 6, ln = tid & 63;
  float s1 = 0.f, s2 = 0.f, s3 = 0.f;
  for (int i = tid; i < NB * NP; i += 1024) {
    float a = rowfd[h * NB * NP + i];
    float c = rowrcd[h * NB * NP + i];
    s1 += a;
    s2 += c;
    s3 += a * c;
  }
#pragma unroll
  for (int mm = 1; mm < 64; mm <<= 1) {
    s1 += __shfl_xor(s1, mm);
    s2 += __shfl_xor(s2, mm);
    s3 += __shfl_xor(s3, mm);
  }
  if (ln == 0) { r1[w] = s1; r2[w] = s2; r3[w] = s3; }
  __syncthreads();
  if (tid == 0) {
    float Sfd = 0.f, Srcd = 0.f, Sdot = 0.f;
#pragma unroll
    for (int i = 0; i < 16; ++i) { Sfd += r1[i]; Srcd += r2[i]; Sdot += r3[i]; }
    losses[h] = -(cross[h] - Sdot * (1.0f / 1024.0f) +
                  (Sfd / NTOT - shifts[h]) * Srcd) / NTOT;
  }
}

__global__ void finalize_combine(const float* __restrict__ losses,
                                 float* __restrict__ out) {
  if (threadIdx.x == 0) {
    out[0] = losses[0];
    out[1] = losses[1];
    out[2] = 0.5f * (losses[2] + losses[3]);
  }
}

// ---------------------------------------------------------------- launch
extern "C" void kernel_launch(void* const* d_in, const int* in_sizes, int n_in,
                              void* d_out, int out_size, void* d_ws, size_t ws_size,
                              hipStream_t stream) {
  (void)in_sizes; (void)n_in; (void)out_size; (void)ws_size;
  const float* orig_feats = (const float*)d_in[0];
  const float* orig_feats_pos = (const float*)d_in[1];
  const float* orig_code = (const float*)d_in[4];
  const float* orig_code_pos = (const float*)d_in[5];
  const float* coords1 = (const float*)d_in[8];
  const float* coords2 = (const float*)d_in[9];
  const int* perms = (const int*)d_in[10];
  float* out = (float*)d_out;

  char* ws = (char*)d_ws;
  size_t off = 0;
  float* featsT = (float*)(ws + off); off += (size_t)NB * HW * CF * 4;
  float* codeT  = (float*)(ws + off); off += (size_t)NB * HW * CC * 4;
  __hip_bfloat16* Fb = (__hip_bfloat16*)(ws + off); off += (size_t)4 * NB * NP * CF * 2;
  __hip_bfloat16* Cb = (__hip_bfloat16*)(ws + off); off += (size_t)4 * NB * NP * CC * 2;
  float* rowfd  = (float*)(ws + off); off += (size_t)4 * NB * NP * 4;
  float* rowrcd = (float*)(ws + off); off += (size_t)4 * NB * NP * 4;
  float* cross  = (float*)(ws + off); off += 64;
  float* losses = (float*)(ws + off); off += 64;
  float* scF    = (float*)(ws + off); off += (size_t)4 * NB * NP * 4;
  float* scC    = (float*)(ws + off); off += (size_t)4 * NB * NP * 4;

  // zero accumulators (rowfd | rowrcd | cross | losses contiguous)
  (void)hipMemsetAsync(rowfd, 0, (size_t)4 * NB * NP * 4 * 2 + 128, stream);

  dim3 tb(32, 8);
  // pass 1: self tensors -> slots 0 (self@c1), 2,3 (neg@c2 permuted)
  transpose_kernel<<<dim3(25, 24, 16), tb, 0, stream>>>(orig_feats, featsT, CF);
  transpose_kernel<<<dim3(25, 16, 16), tb, 0, stream>>>(orig_code, codeT, CC);
  sample_pack_kernel<<<dim3(16, 16, 3), 256, 0, stream>>>(
      featsT, codeT, coords1, coords2, perms, 0, Fb, Cb, scF, scC);
  // pass 2: pos tensors reuse transpose buffers -> slot 1 (pos@c2)
  transpose_kernel<<<dim3(25, 24, 16), tb, 0, stream>>>(orig_feats_pos, featsT, CF);
  transpose_kernel<<<dim3(25, 16, 16), tb, 0, stream>>>(orig_code_pos, codeT, CC);
  sample_pack_kernel<<<dim3(16, 16, 1), 256, 0, stream>>>(
      featsT, codeT, coords1, coords2, perms, 1, Fb, Cb, scF, scC);

  corr_kernel<<<dim3(4096), 256, 0, stream>>>(Fb, Cb, scF, scC,
                                              rowfd, rowrcd, cross);
  finalize_partial<<<4, 1024, 0, stream>>>(rowfd, rowrcd, cross, losses);
  finalize_combine<<<1, 64, 0, stream>>>(losses, out);
}

// Round 5
// 482.137 us; speedup vs baseline: 1.8496x; 1.3173x over previous
//
#include <hip/hip_runtime.h>
#include <hip/hip_bf16.h>

#define NB 16
#define NP 1024
#define CF 768
#define CC 512
#define HH 28
#define WW 28
#define HW 784
#define NTOT 16777216.0f  // 16*1024*1024

typedef short bf16x8 __attribute__((ext_vector_type(8)));
typedef float f32x4 __attribute__((ext_vector_type(4)));
struct __align__(8) bf4 { __hip_bfloat16 a, b, c, d; };

__device__ __forceinline__ float b2f(__hip_bfloat16 h) { return __bfloat162float(h); }

// Supertile layout (UNSCALED bf16; norms applied in corr epilogue):
//   feats: [slot(4)][b(16)][kt(12)][pt(8)] x 1024 chunks of 16B,
//   code : [slot(4)][b(16)][kt(8) ][pt(8)] x 1024 chunks of 16B,
// chunk index = r*128 + m (r in [0,8), m = p&127), payload = 8 bf16 =
// channels [kt*64 + r*8 .. +8) of position row p -- exactly the LDS image
// corr_kernel's MFMA ds_reads consume, so staging is a contiguous 16 KB
// stream. Norm scales scF/scC [slot][b][p] f32 applied as rank-1 diag in the
// corr epilogue (relu commutes with positive scales).

// ---------------------------------------------------------------- transpose
// (B, C, HW) f32 -> [t(2)][b][HW][C] bf16. z encodes t (self/pos) and batch.
__global__ void transpose_bf16_kernel(const float* __restrict__ in0,
                                      const float* __restrict__ in1,
                                      __hip_bfloat16* __restrict__ out, int C) {
  __shared__ float tile[32][33];
  int p0 = blockIdx.x * 32, c0 = blockIdx.y * 32;
  int t = blockIdx.z >> 4, b = blockIdx.z & 15;
  int tx = threadIdx.x, ty = threadIdx.y;
  const float* ib = (t == 0 ? in0 : in1) + (size_t)b * C * HW;
  __hip_bfloat16* ob = out + ((size_t)t * NB + b) * HW * C;
#pragma unroll
  for (int i = 0; i < 32; i += 8) {
    int c = c0 + ty + i, p = p0 + tx;
    if (p < HW) tile[ty + i][tx] = ib[(size_t)c * HW + p];
  }
  __syncthreads();
#pragma unroll
  for (int i = 0; i < 32; i += 8) {
    int p = p0 + ty + i, c = c0 + tx;
    if (p < HW) ob[(size_t)p * C + c] = __float2bfloat16(tile[tx][ty + i]);
  }
}

// ---------------------------------------------------------------- sampling
// One launch, grid (16,16,4): x = 64-position block, y = batch, z = slot.
// slot 0: coords1/self, 1: coords2/pos-tensors, 2,3: coords2/neg (permuted).
// 256 threads = 16 groups x 16 lanes. Per kt-slice (64ch): group g handles
// positions j*16+g, lane l gathers bf16x4 of 4 corners (128B-contig segments),
// combines in f32, accumulates ssq, stages UNSCALED bf16 into an LDS
// supertile image, block flushes 8 KB fully-coalesced. End: write 1/norm.
__global__ __launch_bounds__(256) void sample_pack_kernel(
    const __hip_bfloat16* __restrict__ fTb, const __hip_bfloat16* __restrict__ cTb,
    const float* __restrict__ coords1, const float* __restrict__ coords2,
    const int* __restrict__ perms,
    __hip_bfloat16* __restrict__ Fb, __hip_bfloat16* __restrict__ Cb,
    float* __restrict__ scF, float* __restrict__ scC) {
  __shared__ int offs[4][64];
  __shared__ float wts[4][64];
  __shared__ char tile[8320];  // 512 chunks*16B + 16B pad per r-row

  int bb = blockIdx.y, slot = blockIdx.z;
  int tid = threadIdx.x;
  int p0 = blockIdx.x * 64;
  int pt = blockIdx.x >> 1, mh = blockIdx.x & 1;

  const float* coords = (slot == 0) ? coords1 : coords2;
  int srcidx;  // index into [t(2)][b(16)] transposed buffers
  if (slot == 0)      srcidx = bb;
  else if (slot == 1) srcidx = 16 + bb;
  else if (slot == 2) srcidx = perms[bb];
  else                srcidx = perms[16 + bb];

  if (tid < 64) {
    int p = p0 + tid;
    float cx = coords[((size_t)bb * NP + p) * 2 + 0];
    float cy = coords[((size_t)bb * NP + p) * 2 + 1];
    float x = cx * (WW - 1), y = cy * (HH - 1);  // (c*2-1 +1)*0.5*(W-1)
    float x0f = floorf(x), y0f = floorf(y);
    float wx = x - x0f, wy = y - y0f;
    int x0 = min(max((int)x0f, 0), WW - 1);
    int x1 = min(max((int)x0f + 1, 0), WW - 1);
    int y0 = min(max((int)y0f, 0), HH - 1);
    int y1 = min(max((int)y0f + 1, 0), HH - 1);
    offs[0][tid] = y0 * WW + x0;
    offs[1][tid] = y1 * WW + x0;
    offs[2][tid] = y0 * WW + x1;
    offs[3][tid] = y1 * WW + x1;
    wts[0][tid] = (1.f - wx) * (1.f - wy);
    wts[1][tid] = (1.f - wx) * wy;
    wts[2][tid] = wx * (1.f - wy);
    wts[3][tid] = wx * wy;
  }
  __syncthreads();

  int gid = tid >> 4, l = tid & 15;
  int r = l >> 1, half = l & 1;

  // ---------------- feats (12 kt-slices)
  {
    const __hip_bfloat16* base = fTb + (size_t)srcidx * HW * CF;
    float ssq[4] = {0.f, 0.f, 0.f, 0.f};
    for (int kt = 0; kt < 12; ++kt) {
#pragma unroll
      for (int j = 0; j < 4; ++j) {
        int m = j * 16 + gid;
        float4 v = {0.f, 0.f, 0.f, 0.f};
#pragma unroll
        for (int c = 0; c < 4; ++c) {
          const bf4 t4 = *((const bf4*)(base + (size_t)offs[c][m] * CF) + kt * 16 + l);
          float wv = wts[c][m];
          v.x += wv * b2f(t4.a); v.y += wv * b2f(t4.b);
          v.z += wv * b2f(t4.c); v.w += wv * b2f(t4.d);
        }
        ssq[j] += v.x * v.x + v.y * v.y + v.z * v.z + v.w * v.w;
        bf4 o = {__float2bfloat16(v.x), __float2bfloat16(v.y),
                 __float2bfloat16(v.z), __float2bfloat16(v.w)};
        int cl = r * 64 + m;
        *(bf4*)(tile + cl * 16 + r * 16 + half * 8) = o;
      }
      __syncthreads();
      char* gbase = (char*)Fb +
          (((((size_t)slot * NB + bb) * 12 + kt) * 8 + pt) * 1024 + (size_t)mh * 64) * 16;
#pragma unroll
      for (int jj = 0; jj < 2; ++jj) {
        int cl = jj * 256 + tid;
        int rr = cl >> 6, mi = cl & 63;
        float4 val = *(const float4*)(tile + cl * 16 + rr * 16);
        *(float4*)(gbase + (size_t)(rr * 128 + mi) * 16) = val;
      }
      __syncthreads();
    }
#pragma unroll
    for (int j = 0; j < 4; ++j) {
#pragma unroll
      for (int mm = 1; mm < 16; mm <<= 1) ssq[j] += __shfl_xor(ssq[j], mm);
    }
    if (l == 0) {
#pragma unroll
      for (int j = 0; j < 4; ++j) {
        int p = p0 + j * 16 + gid;
        scF[((size_t)slot * NB + bb) * NP + p] = 1.f / fmaxf(sqrtf(ssq[j]), 1e-10f);
      }
    }
  }

  // ---------------- code (8 kt-slices)
  {
    const __hip_bfloat16* base = cTb + (size_t)srcidx * HW * CC;
    float ssq[4] = {0.f, 0.f, 0.f, 0.f};
    for (int kt = 0; kt < 8; ++kt) {
#pragma unroll
      for (int j = 0; j < 4; ++j) {
        int m = j * 16 + gid;
        float4 v = {0.f, 0.f, 0.f, 0.f};
#pragma unroll
        for (int c = 0; c < 4; ++c) {
          const bf4 t4 = *((const bf4*)(base + (size_t)offs[c][m] * CC) + kt * 16 + l);
          float wv = wts[c][m];
          v.x += wv * b2f(t4.a); v.y += wv * b2f(t4.b);
          v.z += wv * b2f(t4.c); v.w += wv * b2f(t4.d);
        }
        ssq[j] += v.x * v.x + v.y * v.y + v.z * v.z + v.w * v.w;
        bf4 o = {__float2bfloat16(v.x), __float2bfloat16(v.y),
                 __float2bfloat16(v.z), __float2bfloat16(v.w)};
        int cl = r * 64 + m;
        *(bf4*)(tile + cl * 16 + r * 16 + half * 8) = o;
      }
      __syncthreads();
      char* gbase = (char*)Cb +
          (((((size_t)slot * NB + bb) * 8 + kt) * 8 + pt) * 1024 + (size_t)mh * 64) * 16;
#pragma unroll
      for (int jj = 0; jj < 2; ++jj) {
        int cl = jj * 256 + tid;
        int rr = cl >> 6, mi = cl & 63;
        float4 val = *(const float4*)(tile + cl * 16 + rr * 16);
        *(float4*)(gbase + (size_t)(rr * 128 + mi) * 16) = val;
      }
      __syncthreads();
    }
#pragma unroll
    for (int j = 0; j < 4; ++j) {
#pragma unroll
      for (int mm = 1; mm < 16; mm <<= 1) ssq[j] += __shfl_xor(ssq[j], mm);
    }
    if (l == 0) {
#pragma unroll
      for (int j = 0; j < 4; ++j) {
        int p = p0 + j * 16 + gid;
        scC[((size_t)slot * NB + bb) * NP + p] = 1.f / fmaxf(sqrtf(ssq[j]), 1e-10f);
      }
    }
  }
}

// ---------------------------------------------------------------- fused corr
__device__ __forceinline__ void stage_sup(const __hip_bfloat16* __restrict__ st,
                                          bf16x8* buf, int tid) {
#pragma unroll
  for (int i = 0; i < 4; ++i) {
    const __hip_bfloat16* g = st + (size_t)(i * 256 + tid) * 8;
    __builtin_amdgcn_global_load_lds(
        (const __attribute__((address_space(1))) void*)g,
        (__attribute__((address_space(3))) void*)&buf[i * 256 + (tid & 192)],
        16, 0, 0);
  }
}

// grid 4096 linear, decoded so id%8 == z%8: one z's 64 tile-blocks are
// temporally co-resident per XCD (L2-resident operands; FETCH 144 MB).
// Block 256 = 4 waves, each wave 64x64 (4x4 MFMA). Merged K-loop, BK=64.
__global__ __launch_bounds__(256, 2) void corr_kernel(
    const __hip_bfloat16* __restrict__ Fb, const __hip_bfloat16* __restrict__ Cb,
    const float* __restrict__ scF, const float* __restrict__ scC,
    float* __restrict__ rowfd, float* __restrict__ rowrcd,
    float* __restrict__ cross) {
  __shared__ bf16x8 Afs[1024], Bfs[1024], Acs[1024], Bcs[1024];  // 64 KB

  int id = blockIdx.x;
  int zl = id & 7, q = id >> 3;
  int bx = q & 7, by = (q >> 3) & 7, zh = q >> 6;
  int z = zh * 8 + zl;
  int h = z >> 4, bb = z & 15;
  int p0 = bx * 128, q0 = by * 128;
  int tid = threadIdx.x, ln = tid & 63, w = tid >> 6;
  int wm = w >> 1, wn = w & 1, quad = ln >> 4, t16 = ln & 15;

  const __hip_bfloat16* AfB = Fb + (((size_t)bb * 12) * 8 + bx) * 8192;
  const __hip_bfloat16* BfB = Fb + ((((size_t)h * NB + bb) * 12) * 8 + by) * 8192;
  const __hip_bfloat16* AcB = Cb + (((size_t)bb * 8) * 8 + bx) * 8192;
  const __hip_bfloat16* BcB = Cb + ((((size_t)h * NB + bb) * 8) * 8 + by) * 8192;
  const size_t KTSTR = (size_t)8 * 8192;

  f32x4 accf[4][4], accc[4][4];
#pragma unroll
  for (int i = 0; i < 4; ++i)
#pragma unroll
    for (int j = 0; j < 4; ++j) {
      accf[i][j] = (f32x4){0.f, 0.f, 0.f, 0.f};
      accc[i][j] = (f32x4){0.f, 0.f, 0.f, 0.f};
    }

  for (int kt = 0; kt < 12; ++kt) {
    stage_sup(AfB + kt * KTSTR, Afs, tid);
    stage_sup(BfB + kt * KTSTR, Bfs, tid);
    if (kt < 8) {
      stage_sup(AcB + kt * KTSTR, Acs, tid);
      stage_sup(BcB + kt * KTSTR, Bcs, tid);
    }
    __syncthreads();
#pragma unroll
    for (int s = 0; s < 2; ++s) {
      bf16x8 a[4], b[4];
#pragma unroll
      for (int mi = 0; mi < 4; ++mi)
        a[mi] = Afs[s * 512 + quad * 128 + wm * 64 + mi * 16 + t16];
#pragma unroll
      for (int ni = 0; ni < 4; ++ni)
        b[ni] = Bfs[s * 512 + quad * 128 + wn * 64 + ni * 16 + t16];
#pragma unroll
      for (int mi = 0; mi < 4; ++mi)
#pragma unroll
        for (int ni = 0; ni < 4; ++ni)
          accf[mi][ni] = __builtin_amdgcn_mfma_f32_16x16x32_bf16(
              a[mi], b[ni], accf[mi][ni], 0, 0, 0);
    }
    if (kt < 8) {
#pragma unroll
      for (int s = 0; s < 2; ++s) {
        bf16x8 a[4], b[4];
#pragma unroll
        for (int mi = 0; mi < 4; ++mi)
          a[mi] = Acs[s * 512 + quad * 128 + wm * 64 + mi * 16 + t16];
#pragma unroll
        for (int ni = 0; ni < 4; ++ni)
          b[ni] = Bcs[s * 512 + quad * 128 + wn * 64 + ni * 16 + t16];
#pragma unroll
        for (int mi = 0; mi < 4; ++mi)
#pragma unroll
          for (int ni = 0; ni < 4; ++ni)
            accc[mi][ni] = __builtin_amdgcn_mfma_f32_16x16x32_bf16(
                a[mi], b[ni], accc[mi][ni], 0, 0, 0);
      }
    }
    __syncthreads();
  }

  // ---- stage norm scales into LDS (reuse Afs)
  float* sm = (float*)Afs;
  {
    const float* s0 = scF + (size_t)bb * NP;
    const float* s1 = scF + ((size_t)h * NB + bb) * NP;
    const float* s2 = scC + (size_t)bb * NP;
    const float* s3 = scC + ((size_t)h * NB + bb) * NP;
    if (tid < 128) {
      sm[tid] = s0[p0 + tid];
      sm[256 + tid] = s2[p0 + tid];
    } else {
      int u = tid - 128;
      sm[128 + u] = s1[q0 + u];
      sm[384 + u] = s3[q0 + u];
    }
  }
  __syncthreads();

  // ---- epilogue: C/D layout row = quad*4 + reg, col = t16; apply scales
  float sbf[4], sbc[4];
#pragma unroll
  for (int ni = 0; ni < 4; ++ni) {
    int qq = wn * 64 + ni * 16 + t16;
    sbf[ni] = sm[128 + qq];
    sbc[ni] = sm[384 + qq];
  }
  float cross_l = 0.f;
#pragma unroll
  for (int mi = 0; mi < 4; ++mi) {
#pragma unroll
    for (int r = 0; r < 4; ++r) {
      int pl = wm * 64 + mi * 16 + quad * 4 + r;
      float saf = sm[pl], sac = sm[256 + pl];
      float sfd = 0.f, srw = 0.f;
#pragma unroll
      for (int ni = 0; ni < 4; ++ni) {
        float fd = accf[mi][ni][r] * (saf * sbf[ni]);
        float cd = accc[mi][ni][r] * (sac * sbc[ni]);
        float rc = fmaxf(cd, 0.f);
        sfd += fd;
        srw += rc;
        cross_l += rc * fd;
      }
#pragma unroll
      for (int mm = 1; mm < 16; mm <<= 1) {
        sfd += __shfl_xor(sfd, mm);
        srw += __shfl_xor(srw, mm);
      }
      if (t16 == 0) {
        int p = p0 + pl;
        size_t idx = ((size_t)h * NB + bb) * NP + p;
        atomicAdd(&rowfd[idx], sfd);
        atomicAdd(&rowrcd[idx], srw);
      }
    }
  }
#pragma unroll
  for (int mm = 1; mm < 64; mm <<= 1) cross_l += __shfl_xor(cross_l, mm);
  float* crs = (float*)Bfs;
  if (ln == 0) crs[w] = cross_l;
  __syncthreads();
  if (tid == 0) atomicAdd(&cross[h], crs[0] + crs[1] + crs[2] + crs[3]);
}

// ---------------------------------------------------------------- finalize
__global__ void finalize_partial(const float* __restrict__ rowfd,
                                 const float* __restrict__ rowrcd,
                                 const float* __restrict__ cross,
                                 float* __restrict__ losses) {
  __shared__ float r1[16], r2[16], r3[16];
  const float shifts[4] = {0.18f, 0.12f, 0.46f, 0.46f};
  int h = blockIdx.x, tid = threadIdx.x, w = tid >> 6, ln = tid & 63;
  float s1 = 0.f, s2 = 0.f, s3 = 0.f;
  for (int i = tid; i < NB * NP; i += 1024) {
    float a = rowfd[h * NB * NP + i];
    float c = rowrcd[h * NB * NP + i];
    s1 += a;
    s2 += c;
    s3 += a * c;
  }
#pragma unroll
  for (int mm = 1; mm < 64; mm <<= 1) {
    s1 += __shfl_xor(s1, mm);
    s2 += __shfl_xor(s2, mm);
    s3 += __shfl_xor(s3, mm);
  }
  if (ln == 0) { r1[w] = s1; r2[w] = s2; r3[w] = s3; }
  __syncthreads();
  if (tid == 0) {
    float Sfd = 0.f, Srcd = 0.f, Sdot = 0.f;
#pragma unroll
    for (int i = 0; i < 16; ++i) { Sfd += r1[i]; Srcd += r2[i]; Sdot += r3[i]; }
    losses[h] = -(cross[h] - Sdot * (1.0f / 1024.0f) +
                  (Sfd / NTOT - shifts[h]) * Srcd) / NTOT;
  }
}

__global__ void finalize_combine(const float* __restrict__ losses,
                                 float* __restrict__ out) {
  if (threadIdx.x == 0) {
    out[0] = losses[0];
    out[1] = losses[1];
    out[2] = 0.5f * (losses[2] + losses[3]);
  }
}

// ---------------------------------------------------------------- launch
extern "C" void kernel_launch(void* const* d_in, const int* in_sizes, int n_in,
                              void* d_out, int out_size, void* d_ws, size_t ws_size,
                              hipStream_t stream) {
  (void)in_sizes; (void)n_in; (void)out_size; (void)ws_size;
  const float* orig_feats = (const float*)d_in[0];
  const float* orig_feats_pos = (const float*)d_in[1];
  const float* orig_code = (const float*)d_in[4];
  const float* orig_code_pos = (const float*)d_in[5];
  const float* coords1 = (const float*)d_in[8];
  const float* coords2 = (const float*)d_in[9];
  const int* perms = (const int*)d_in[10];
  float* out = (float*)d_out;

  char* ws = (char*)d_ws;
  size_t off = 0;
  __hip_bfloat16* fTb = (__hip_bfloat16*)(ws + off); off += (size_t)2 * NB * HW * CF * 2;
  __hip_bfloat16* cTb = (__hip_bfloat16*)(ws + off); off += (size_t)2 * NB * HW * CC * 2;
  __hip_bfloat16* Fb = (__hip_bfloat16*)(ws + off); off += (size_t)4 * NB * NP * CF * 2;
  __hip_bfloat16* Cb = (__hip_bfloat16*)(ws + off); off += (size_t)4 * NB * NP * CC * 2;
  float* rowfd  = (float*)(ws + off); off += (size_t)4 * NB * NP * 4;
  float* rowrcd = (float*)(ws + off); off += (size_t)4 * NB * NP * 4;
  float* cross  = (float*)(ws + off); off += 64;
  float* losses = (float*)(ws + off); off += 64;
  float* scF    = (float*)(ws + off); off += (size_t)4 * NB * NP * 4;
  float* scC    = (float*)(ws + off); off += (size_t)4 * NB * NP * 4;

  // zero accumulators (rowfd | rowrcd | cross | losses contiguous)
  (void)hipMemsetAsync(rowfd, 0, (size_t)4 * NB * NP * 4 * 2 + 128, stream);

  dim3 tb(32, 8);
  transpose_bf16_kernel<<<dim3(25, 24, 32), tb, 0, stream>>>(
      orig_feats, orig_feats_pos, fTb, CF);
  transpose_bf16_kernel<<<dim3(25, 16, 32), tb, 0, stream>>>(
      orig_code, orig_code_pos, cTb, CC);
  sample_pack_kernel<<<dim3(16, 16, 4), 256, 0, stream>>>(
      fTb, cTb, coords1, coords2, perms, Fb, Cb, scF, scC);

  corr_kernel<<<dim3(4096), 256, 0, stream>>>(Fb, Cb, scF, scC,
                                              rowfd, rowrcd, cross);
  finalize_partial<<<4, 1024, 0, stream>>>(rowfd, rowrcd, cross, losses);
  finalize_combine<<<1, 64, 0, stream>>>(losses, out);
}

// Round 6
// 417.585 us; speedup vs baseline: 2.1355x; 1.1546x over previous
//
#include <hip/hip_runtime.h>
#include <hip/hip_bf16.h>

#define NB 16
#define NP 1024
#define CF 768
#define CC 512
#define HH 28
#define WW 28
#define HW 784
#define NTOT 16777216.0f  // 16*1024*1024

typedef float f32x4 __attribute__((ext_vector_type(4)));
struct __align__(8) bf4 { __hip_bfloat16 a, b, c, d; };

__device__ __forceinline__ float b2f(__hip_bfloat16 h) { return __bfloat162float(h); }

// Supertile layout (UNSCALED fp8 e4m3; norms applied in corr epilogue):
//   feats: [slot(4)][b(16)][kt(12)][pt(8)] x 1024 chunks of 8B,
//   code : [slot(4)][b(16)][kt(8) ][pt(8)] x 1024 chunks of 8B,
// chunk index = r*128 + m (r in [0,8), m = p&127), payload = 8 fp8 =
// channels [kt*64 + r*8 .. +8) of position row p -- exactly the LDS image
// corr_kernel's MFMA ds_reads consume (fp8 16x16x32 A/B frag: lane%16 = row,
// k = (lane/16)*8 + byte, same structure as the verified bf16 variant).
// Staging is a contiguous 8 KB stream per supertile. Norm scales scF/scC
// f32, applied as rank-1 diag in the corr epilogue (relu commutes with
// positive scales; fp8 rounding is RNE -> unbiased).

// ---------------------------------------------------------------- transpose
// (B, C, HW) f32 -> [t(2)][b][HW][C] bf16. z encodes t (self/pos) and batch.
__global__ void transpose_bf16_kernel(const float* __restrict__ in0,
                                      const float* __restrict__ in1,
                                      __hip_bfloat16* __restrict__ out, int C) {
  __shared__ float tile[32][33];
  int p0 = blockIdx.x * 32, c0 = blockIdx.y * 32;
  int t = blockIdx.z >> 4, b = blockIdx.z & 15;
  int tx = threadIdx.x, ty = threadIdx.y;
  const float* ib = (t == 0 ? in0 : in1) + (size_t)b * C * HW;
  __hip_bfloat16* ob = out + ((size_t)t * NB + b) * HW * C;
#pragma unroll
  for (int i = 0; i < 32; i += 8) {
    int c = c0 + ty + i, p = p0 + tx;
    if (p < HW) tile[ty + i][tx] = ib[(size_t)c * HW + p];
  }
  __syncthreads();
#pragma unroll
  for (int i = 0; i < 32; i += 8) {
    int p = p0 + ty + i, c = c0 + tx;
    if (p < HW) ob[(size_t)p * C + c] = __float2bfloat16(tile[tx][ty + i]);
  }
}

// ---------------------------------------------------------------- sampling
// One launch, grid (16,16,4): x = 64-position block, y = batch, z = slot.
// slot 0: coords1/self, 1: coords2/pos-tensors, 2,3: coords2/neg (permuted).
// 256 threads = 16 groups x 16 lanes. Per kt-slice (64ch): group g handles
// positions j*16+g, lane l gathers bf16x4 of 4 corners (128B-contig
// segments), combines in f32, accumulates ssq, packs fp8 via
// v_cvt_pk_fp8_f32 into an LDS supertile image, block flushes 4 KB
// fully-coalesced. End: write 1/norm.
__global__ __launch_bounds__(256) void sample_pack_kernel(
    const __hip_bfloat16* __restrict__ fTb, const __hip_bfloat16* __restrict__ cTb,
    const float* __restrict__ coords1, const float* __restrict__ coords2,
    const int* __restrict__ perms,
    unsigned char* __restrict__ Fb, unsigned char* __restrict__ Cb,
    float* __restrict__ scF, float* __restrict__ scC) {
  __shared__ int offs[4][64];
  __shared__ float wts[4][64];
  __shared__ char tile[4160];  // 8 r-rows x (64 chunks*8B + 8B pad)

  int bb = blockIdx.y, slot = blockIdx.z;
  int tid = threadIdx.x;
  int p0 = blockIdx.x * 64;
  int pt = blockIdx.x >> 1, mh = blockIdx.x & 1;

  const float* coords = (slot == 0) ? coords1 : coords2;
  int srcidx;  // index into [t(2)][b(16)] transposed buffers
  if (slot == 0)      srcidx = bb;
  else if (slot == 1) srcidx = 16 + bb;
  else if (slot == 2) srcidx = perms[bb];
  else                srcidx = perms[16 + bb];

  if (tid < 64) {
    int p = p0 + tid;
    float cx = coords[((size_t)bb * NP + p) * 2 + 0];
    float cy = coords[((size_t)bb * NP + p) * 2 + 1];
    float x = cx * (WW - 1), y = cy * (HH - 1);  // (c*2-1 +1)*0.5*(W-1)
    float x0f = floorf(x), y0f = floorf(y);
    float wx = x - x0f, wy = y - y0f;
    int x0 = min(max((int)x0f, 0), WW - 1);
    int x1 = min(max((int)x0f + 1, 0), WW - 1);
    int y0 = min(max((int)y0f, 0), HH - 1);
    int y1 = min(max((int)y0f + 1, 0), HH - 1);
    offs[0][tid] = y0 * WW + x0;
    offs[1][tid] = y1 * WW + x0;
    offs[2][tid] = y0 * WW + x1;
    offs[3][tid] = y1 * WW + x1;
    wts[0][tid] = (1.f - wx) * (1.f - wy);
    wts[1][tid] = (1.f - wx) * wy;
    wts[2][tid] = wx * (1.f - wy);
    wts[3][tid] = wx * wy;
  }
  __syncthreads();

  int gid = tid >> 4, l = tid & 15;
  int r = l >> 1, h4 = l & 1;

  // ---------------- feats (12 kt-slices)
  {
    const __hip_bfloat16* base = fTb + (size_t)srcidx * HW * CF;
    float ssq[4] = {0.f, 0.f, 0.f, 0.f};
    for (int kt = 0; kt < 12; ++kt) {
#pragma unroll
      for (int j = 0; j < 4; ++j) {
        int m = j * 16 + gid;
        float4 v = {0.f, 0.f, 0.f, 0.f};
#pragma unroll
        for (int c = 0; c < 4; ++c) {
          const bf4 t4 = *((const bf4*)(base + (size_t)offs[c][m] * CF) + kt * 16 + l);
          float wv = wts[c][m];
          v.x += wv * b2f(t4.a); v.y += wv * b2f(t4.b);
          v.z += wv * b2f(t4.c); v.w += wv * b2f(t4.d);
        }
        ssq[j] += v.x * v.x + v.y * v.y + v.z * v.z + v.w * v.w;
        int w0 = __builtin_amdgcn_cvt_pk_fp8_f32(v.x, v.y, 0, false);
        int w1 = __builtin_amdgcn_cvt_pk_fp8_f32(v.z, v.w, w0, true);
        *(int*)(tile + r * 520 + m * 8 + h4 * 4) = w1;
      }
      __syncthreads();
      unsigned char* gbase = Fb +
          (((((size_t)slot * NB + bb) * 12 + kt) * 8 + pt) * 1024 + (size_t)mh * 64) * 8;
#pragma unroll
      for (int jj = 0; jj < 2; ++jj) {
        int cl = jj * 256 + tid;
        int rr = cl >> 6, mi = cl & 63;
        unsigned long long val = *(const unsigned long long*)(tile + rr * 520 + mi * 8);
        *(unsigned long long*)(gbase + (size_t)(rr * 128 + mi) * 8) = val;
      }
      __syncthreads();
    }
#pragma unroll
    for (int j = 0; j < 4; ++j) {
#pragma unroll
      for (int mm = 1; mm < 16; mm <<= 1) ssq[j] += __shfl_xor(ssq[j], mm);
    }
    if (l == 0) {
#pragma unroll
      for (int j = 0; j < 4; ++j) {
        int p = p0 + j * 16 + gid;
        scF[((size_t)slot * NB + bb) * NP + p] = 1.f / fmaxf(sqrtf(ssq[j]), 1e-10f);
      }
    }
  }

  // ---------------- code (8 kt-slices)
  {
    const __hip_bfloat16* base = cTb + (size_t)srcidx * HW * CC;
    float ssq[4] = {0.f, 0.f, 0.f, 0.f};
    for (int kt = 0; kt < 8; ++kt) {
#pragma unroll
      for (int j = 0; j < 4; ++j) {
        int m = j * 16 + gid;
        float4 v = {0.f, 0.f, 0.f, 0.f};
#pragma unroll
        for (int c = 0; c < 4; ++c) {
          const bf4 t4 = *((const bf4*)(base + (size_t)offs[c][m] * CC) + kt * 16 + l);
          float wv = wts[c][m];
          v.x += wv * b2f(t4.a); v.y += wv * b2f(t4.b);
          v.z += wv * b2f(t4.c); v.w += wv * b2f(t4.d);
        }
        ssq[j] += v.x * v.x + v.y * v.y + v.z * v.z + v.w * v.w;
        int w0 = __builtin_amdgcn_cvt_pk_fp8_f32(v.x, v.y, 0, false);
        int w1 = __builtin_amdgcn_cvt_pk_fp8_f32(v.z, v.w, w0, true);
        *(int*)(tile + r * 520 + m * 8 + h4 * 4) = w1;
      }
      __syncthreads();
      unsigned char* gbase = Cb +
          (((((size_t)slot * NB + bb) * 8 + kt) * 8 + pt) * 1024 + (size_t)mh * 64) * 8;
#pragma unroll
      for (int jj = 0; jj < 2; ++jj) {
        int cl = jj * 256 + tid;
        int rr = cl >> 6, mi = cl & 63;
        unsigned long long val = *(const unsigned long long*)(tile + rr * 520 + mi * 8);
        *(unsigned long long*)(gbase + (size_t)(rr * 128 + mi) * 8) = val;
      }
      __syncthreads();
    }
#pragma unroll
    for (int j = 0; j < 4; ++j) {
#pragma unroll
      for (int mm = 1; mm < 16; mm <<= 1) ssq[j] += __shfl_xor(ssq[j], mm);
    }
    if (l == 0) {
#pragma unroll
      for (int j = 0; j < 4; ++j) {
        int p = p0 + j * 16 + gid;
        scC[((size_t)slot * NB + bb) * NP + p] = 1.f / fmaxf(sqrtf(ssq[j]), 1e-10f);
      }
    }
  }
}

// ---------------------------------------------------------------- fused corr
// Stage one 8 KB fp8 supertile (contiguous in global) into LDS.
__device__ __forceinline__ void stage_sup(const unsigned long long* __restrict__ st,
                                          unsigned long long* buf, int tid) {
#pragma unroll
  for (int i = 0; i < 2; ++i) {
    const char* g = (const char*)st + (size_t)(i * 256 + tid) * 16;
    char* d = (char*)buf + i * 4096 + (tid & 192) * 16;
    __builtin_amdgcn_global_load_lds(
        (const __attribute__((address_space(1))) void*)g,
        (__attribute__((address_space(3))) void*)d, 16, 0, 0);
  }
}

// grid 4096 linear, decoded so id%8 == z%8: one z's 64 tile-blocks are
// temporally co-resident per XCD (L2-resident operands). Block 256 = 4 waves,
// each wave 64x64 (4x4 MFMA), fp8 e4m3 operands. Merged K-loop, BK=64.
__global__ __launch_bounds__(256, 2) void corr_kernel(
    const unsigned long long* __restrict__ Fb,
    const unsigned long long* __restrict__ Cb,
    const float* __restrict__ scF, const float* __restrict__ scC,
    float* __restrict__ rowfd, float* __restrict__ rowrcd,
    float* __restrict__ cross) {
  __shared__ unsigned long long Afs[1024], Bfs[1024], Acs[1024], Bcs[1024];  // 32 KB

  int id = blockIdx.x;
  int zl = id & 7, q = id >> 3;
  int bx = q & 7, by = (q >> 3) & 7, zh = q >> 6;
  int z = zh * 8 + zl;
  int h = z >> 4, bb = z & 15;
  int p0 = bx * 128, q0 = by * 128;
  int tid = threadIdx.x, ln = tid & 63, w = tid >> 6;
  int wm = w >> 1, wn = w & 1, quad = ln >> 4, t16 = ln & 15;

  const unsigned long long* AfB = Fb + (((size_t)bb * 12) * 8 + bx) * 1024;
  const unsigned long long* BfB = Fb + ((((size_t)h * NB + bb) * 12) * 8 + by) * 1024;
  const unsigned long long* AcB = Cb + (((size_t)bb * 8) * 8 + bx) * 1024;
  const unsigned long long* BcB = Cb + ((((size_t)h * NB + bb) * 8) * 8 + by) * 1024;
  const size_t KTSTR = (size_t)8 * 1024;  // one kt step = 8 supertiles

  f32x4 accf[4][4], accc[4][4];
#pragma unroll
  for (int i = 0; i < 4; ++i)
#pragma unroll
    for (int j = 0; j < 4; ++j) {
      accf[i][j] = (f32x4){0.f, 0.f, 0.f, 0.f};
      accc[i][j] = (f32x4){0.f, 0.f, 0.f, 0.f};
    }

  for (int kt = 0; kt < 12; ++kt) {
    stage_sup(AfB + kt * KTSTR, Afs, tid);
    stage_sup(BfB + kt * KTSTR, Bfs, tid);
    if (kt < 8) {
      stage_sup(AcB + kt * KTSTR, Acs, tid);
      stage_sup(BcB + kt * KTSTR, Bcs, tid);
    }
    __syncthreads();
#pragma unroll
    for (int s = 0; s < 2; ++s) {
      long a[4], b[4];
#pragma unroll
      for (int mi = 0; mi < 4; ++mi)
        a[mi] = (long)Afs[s * 512 + quad * 128 + wm * 64 + mi * 16 + t16];
#pragma unroll
      for (int ni = 0; ni < 4; ++ni)
        b[ni] = (long)Bfs[s * 512 + quad * 128 + wn * 64 + ni * 16 + t16];
#pragma unroll
      for (int mi = 0; mi < 4; ++mi)
#pragma unroll
        for (int ni = 0; ni < 4; ++ni)
          accf[mi][ni] = __builtin_amdgcn_mfma_f32_16x16x32_fp8_fp8(
              a[mi], b[ni], accf[mi][ni], 0, 0, 0);
    }
    if (kt < 8) {
#pragma unroll
      for (int s = 0; s < 2; ++s) {
        long a[4], b[4];
#pragma unroll
        for (int mi = 0; mi < 4; ++mi)
          a[mi] = (long)Acs[s * 512 + quad * 128 + wm * 64 + mi * 16 + t16];
#pragma unroll
        for (int ni = 0; ni < 4; ++ni)
          b[ni] = (long)Bcs[s * 512 + quad * 128 + wn * 64 + ni * 16 + t16];
#pragma unroll
        for (int mi = 0; mi < 4; ++mi)
#pragma unroll
          for (int ni = 0; ni < 4; ++ni)
            accc[mi][ni] = __builtin_amdgcn_mfma_f32_16x16x32_fp8_fp8(
                a[mi], b[ni], accc[mi][ni], 0, 0, 0);
      }
    }
    __syncthreads();
  }

  // ---- stage norm scales into LDS (reuse Afs)
  float* sm = (float*)Afs;
  {
    const float* s0 = scF + (size_t)bb * NP;
    const float* s1 = scF + ((size_t)h * NB + bb) * NP;
    const float* s2 = scC + (size_t)bb * NP;
    const float* s3 = scC + ((size_t)h * NB + bb) * NP;
    if (tid < 128) {
      sm[tid] = s0[p0 + tid];
      sm[256 + tid] = s2[p0 + tid];
    } else {
      int u = tid - 128;
      sm[128 + u] = s1[q0 + u];
      sm[384 + u] = s3[q0 + u];
    }
  }
  __syncthreads();

  // ---- epilogue: C/D layout row = quad*4 + reg, col = t16; apply scales
  float sbf[4], sbc[4];
#pragma unroll
  for (int ni = 0; ni < 4; ++ni) {
    int qq = wn * 64 + ni * 16 + t16;
    sbf[ni] = sm[128 + qq];
    sbc[ni] = sm[384 + qq];
  }
  float cross_l = 0.f;
#pragma unroll
  for (int mi = 0; mi < 4; ++mi) {
#pragma unroll
    for (int r = 0; r < 4; ++r) {
      int pl = wm * 64 + mi * 16 + quad * 4 + r;
      float saf = sm[pl], sac = sm[256 + pl];
      float sfd = 0.f, srw = 0.f;
#pragma unroll
      for (int ni = 0; ni < 4; ++ni) {
        float fd = accf[mi][ni][r] * (saf * sbf[ni]);
        float cd = accc[mi][ni][r] * (sac * sbc[ni]);
        float rc = fmaxf(cd, 0.f);
        sfd += fd;
        srw += rc;
        cross_l += rc * fd;
      }
#pragma unroll
      for (int mm = 1; mm < 16; mm <<= 1) {
        sfd += __shfl_xor(sfd, mm);
        srw += __shfl_xor(srw, mm);
      }
      if (t16 == 0) {
        int p = p0 + pl;
        size_t idx = ((size_t)h * NB + bb) * NP + p;
        atomicAdd(&rowfd[idx], sfd);
        atomicAdd(&rowrcd[idx], srw);
      }
    }
  }
#pragma unroll
  for (int mm = 1; mm < 64; mm <<= 1) cross_l += __shfl_xor(cross_l, mm);
  float* crs = (float*)Bfs;
  if (ln == 0) crs[w] = cross_l;
  __syncthreads();
  if (tid == 0) atomicAdd(&cross[h], crs[0] + crs[1] + crs[2] + crs[3]);
}

// ---------------------------------------------------------------- finalize
__global__ void finalize_partial(const float* __restrict__ rowfd,
                                 const float* __restrict__ rowrcd,
                                 const float* __restrict__ cross,
                                 float* __restrict__ losses) {
  __shared__ float r1[16], r2[16], r3[16];
  const float shifts[4] = {0.18f, 0.12f, 0.46f, 0.46f};
  int h = blockIdx.x, tid = threadIdx.x, w = tid >> 6, ln = tid & 63;
  float s1 = 0.f, s2 = 0.f, s3 = 0.f;
  for (int i = tid; i < NB * NP; i += 1024) {
    float a = rowfd[h * NB * NP + i];
    float c = rowrcd[h * NB * NP + i];
    s1 += a;
    s2 += c;
    s3 += a * c;
  }
#pragma unroll
  for (int mm = 1; mm < 64; mm <<= 1) {
    s1 += __shfl_xor(s1, mm);
    s2 += __shfl_xor(s2, mm);
    s3 += __shfl_xor(s3, mm);
  }
  if (ln == 0) { r1[w] = s1; r2[w] = s2; r3[w] = s3; }
  __syncthreads();
  if (tid == 0) {
    float Sfd = 0.f, Srcd = 0.f, Sdot = 0.f;
#pragma unroll
    for (int i = 0; i < 16; ++i) { Sfd += r1[i]; Srcd += r2[i]; Sdot += r3[i]; }
    losses[h] = -(cross[h] - Sdot * (1.0f / 1024.0f) +
                  (Sfd / NTOT - shifts[h]) * Srcd) / NTOT;
  }
}

__global__ void finalize_combine(const float* __restrict__ losses,
                                 float* __restrict__ out) {
  if (threadIdx.x == 0) {
    out[0] = losses[0];
    out[1] = losses[1];
    out[2] = 0.5f * (losses[2] + losses[3]);
  }
}

// ---------------------------------------------------------------- launch
extern "C" void kernel_launch(void* const* d_in, const int* in_sizes, int n_in,
                              void* d_out, int out_size, void* d_ws, size_t ws_size,
                              hipStream_t stream) {
  (void)in_sizes; (void)n_in; (void)out_size; (void)ws_size;
  const float* orig_feats = (const float*)d_in[0];
  const float* orig_feats_pos = (const float*)d_in[1];
  const float* orig_code = (const float*)d_in[4];
  const float* orig_code_pos = (const float*)d_in[5];
  const float* coords1 = (const float*)d_in[8];
  const float* coords2 = (const float*)d_in[9];
  const int* perms = (const int*)d_in[10];
  float* out = (float*)d_out;

  char* ws = (char*)d_ws;
  size_t off = 0;
  __hip_bfloat16* fTb = (__hip_bfloat16*)(ws + off); off += (size_t)2 * NB * HW * CF * 2;
  __hip_bfloat16* cTb = (__hip_bfloat16*)(ws + off); off += (size_t)2 * NB * HW * CC * 2;
  unsigned char* Fb = (unsigned char*)(ws + off); off += (size_t)4 * NB * NP * CF;  // fp8
  unsigned char* Cb = (unsigned char*)(ws + off); off += (size_t)4 * NB * NP * CC;  // fp8
  float* rowfd  = (float*)(ws + off); off += (size_t)4 * NB * NP * 4;
  float* rowrcd = (float*)(ws + off); off += (size_t)4 * NB * NP * 4;
  float* cross  = (float*)(ws + off); off += 64;
  float* losses = (float*)(ws + off); off += 64;
  float* scF    = (float*)(ws + off); off += (size_t)4 * NB * NP * 4;
  float* scC    = (float*)(ws + off); off += (size_t)4 * NB * NP * 4;

  // zero accumulators (rowfd | rowrcd | cross | losses contiguous)
  (void)hipMemsetAsync(rowfd, 0, (size_t)4 * NB * NP * 4 * 2 + 128, stream);

  dim3 tb(32, 8);
  transpose_bf16_kernel<<<dim3(25, 24, 32), tb, 0, stream>>>(
      orig_feats, orig_feats_pos, fTb, CF);
  transpose_bf16_kernel<<<dim3(25, 16, 32), tb, 0, stream>>>(
      orig_code, orig_code_pos, cTb, CC);
  sample_pack_kernel<<<dim3(16, 16, 4), 256, 0, stream>>>(
      fTb, cTb, coords1, coords2, perms, Fb, Cb, scF, scC);

  corr_kernel<<<dim3(4096), 256, 0, stream>>>(
      (const unsigned long long*)Fb, (const unsigned long long*)Cb,
      scF, scC, rowfd, rowrcd, cross);
  finalize_partial<<<4, 1024, 0, stream>>>(rowfd, rowrcd, cross, losses);
  finalize_combine<<<1, 64, 0, stream>>>(losses, out);
}